// Round 8
// baseline (36342.651 us; speedup 1.0000x reference)
//
#include <hip/hip_runtime.h>
#include <hip/hip_cooperative_groups.h>

namespace cg = cooperative_groups;

#define T_STEPS 256
// sizes: M=4 N=48 H1=4160 HID=2320 3HID=6960 H2=768 OUT=192 KGIN=52

// ---------------- ws byte-offset layout ----------------
#define O_BAR   0                  // 10 u32 barrier state (memset each launch)
#define O_ZP    256                // 96*4 f32 z-partials
#define O_HF    2048               // 2 x 2320 f32 (h state, parity)
#define HF_STR  9280
#define O_HB    20608              // 2 x 2336 bf16 (h state bf16, parity)
#define HB_STR  4672
#define O_GI    30208              // 6960 f32
#define O_GH    58048              // 6960 f32
#define O_WIH   86016              // 6960*4160 bf16
#define O_WHH   57993216           // 6960*2320 bf16
#define O_W2B   90287616           // 768*2320 bf16
#define NEED_MIN 93851136
#define O_W1P   93851136           // 4160*56 bf16 (padded W1)
#define NEED_FULL 94317056

#define N_IH  28953600
#define N_HH  16147200
#define N_W2  1781760

// legacy fp32-path offsets (float units) for fallback kernel
#define WS_L1  0
#define WS_H0  4160
#define WS_H1  6480
#define WS_L2  8800
#define WS_V   9568
#define WS_C   12640

typedef __attribute__((ext_vector_type(8))) short bf16x8;
typedef __attribute__((ext_vector_type(4))) float f32x4;

__device__ __forceinline__ float wred(float v) {
#pragma unroll
  for (int m = 32; m; m >>= 1) v += __shfl_xor(v, m, 64);
  return v;
}
__device__ __forceinline__ float dot4(float4 a, float4 b) {
  return a.x * b.x + a.y * b.y + a.z * b.z + a.w * b.w;
}
__device__ __forceinline__ float blo(unsigned u) {
  unsigned t = u << 16; return __builtin_bit_cast(float, t);
}
__device__ __forceinline__ float bhi(unsigned u) {
  unsigned t = u & 0xFFFF0000u; return __builtin_bit_cast(float, t);
}
__device__ __forceinline__ float dot8bb(uint4 w, uint4 x) {
  float s;
  s  = blo(w.x) * blo(x.x) + bhi(w.x) * bhi(x.x);
  s += blo(w.y) * blo(x.y) + bhi(w.y) * bhi(x.y);
  s += blo(w.z) * blo(x.z) + bhi(w.z) * bhi(x.z);
  s += blo(w.w) * blo(x.w) + bhi(w.w) * bhi(x.w);
  return s;
}
__device__ __forceinline__ unsigned short f2bf(float f) {  // RNE
  unsigned u = __builtin_bit_cast(unsigned, f);
  unsigned r = u + 0x7FFF + ((u >> 16) & 1);
  return (unsigned short)(r >> 16);
}

// ---- scoped accessors: cross-block data via coherence point, no invalidates
__device__ __forceinline__ void st_ag_f32(float* p, float v) {
  __hip_atomic_store(p, v, __ATOMIC_RELAXED, __HIP_MEMORY_SCOPE_AGENT);
}
__device__ __forceinline__ float ld_ag_f32(const float* p) {
  return __hip_atomic_load(p, __ATOMIC_RELAXED, __HIP_MEMORY_SCOPE_AGENT);
}
__device__ __forceinline__ void st_ag_u32(unsigned* p, unsigned v) {
  __hip_atomic_store(p, v, __ATOMIC_RELAXED, __HIP_MEMORY_SCOPE_AGENT);
}
__device__ __forceinline__ unsigned long long ld_ag_u64(const unsigned long long* p) {
  return __hip_atomic_load(p, __ATOMIC_RELAXED, __HIP_MEMORY_SCOPE_AGENT);
}

// ---------- two-level grid barrier: release-arrive, RELAXED polls ----------
template<int GSZ>
__device__ __forceinline__ void gbar(unsigned* bar, int bid, unsigned target) {
  __syncthreads();
  if (threadIdx.x == 0) {
    unsigned* grp   = bar + (bid & 7);
    unsigned* lead  = bar + 8;
    unsigned* epoch = bar + 9;
    unsigned old = __hip_atomic_fetch_add(grp, 1u, __ATOMIC_RELEASE, __HIP_MEMORY_SCOPE_AGENT);
    if (old == (unsigned)(GSZ - 1)) {
      __hip_atomic_store(grp, 0u, __ATOMIC_RELAXED, __HIP_MEMORY_SCOPE_AGENT);
      unsigned lo = __hip_atomic_fetch_add(lead, 1u, __ATOMIC_ACQ_REL, __HIP_MEMORY_SCOPE_AGENT);
      if (lo == 7u) {
        __hip_atomic_store(lead, 0u, __ATOMIC_RELAXED, __HIP_MEMORY_SCOPE_AGENT);
        __hip_atomic_store(epoch, target, __ATOMIC_RELEASE, __HIP_MEMORY_SCOPE_AGENT);
      } else {
        while (__hip_atomic_load(epoch, __ATOMIC_RELAXED, __HIP_MEMORY_SCOPE_AGENT) < target)
          __builtin_amdgcn_s_sleep(1);
      }
    } else {
      while (__hip_atomic_load(epoch, __ATOMIC_RELAXED, __HIP_MEMORY_SCOPE_AGENT) < target)
        __builtin_amdgcn_s_sleep(1);
    }
  }
  __syncthreads();
}

// ---------------- pre-pass conversion kernels ----------------
__global__ __launch_bounds__(256) void k_cvt(const float4* __restrict__ src,
                                             ushort4* __restrict__ dst, int n4) {
  int i = blockIdx.x * 256 + threadIdx.x, st = gridDim.x * 256;
  for (; i < n4; i += st) {
    float4 v = src[i];
    ushort4 o;
    o.x = f2bf(v.x); o.y = f2bf(v.y); o.z = f2bf(v.z); o.w = f2bf(v.w);
    dst[i] = o;
  }
}
__global__ __launch_bounds__(256) void k_cvtw1(const float* __restrict__ W1,
                                               unsigned short* __restrict__ dst) {
  int i = blockIdx.x * 256 + threadIdx.x;           // over 4160*56
  if (i < 4160 * 56) {
    int r = i / 56, c = i - r * 56;
    dst[i] = (c < 52) ? f2bf(W1[r * 52 + c]) : (unsigned short)0;
  }
}
__global__ __launch_bounds__(256) void k_h0(const float* __restrict__ h0,
                                            unsigned short* __restrict__ hb0,
                                            unsigned short* __restrict__ hb1) {
  int j = blockIdx.x * 256 + threadIdx.x;
  if (j < 2336) {
    hb1[j] = (j < 2320) ? f2bf(h0[j]) : (unsigned short)0;
    if (j >= 2320) hb0[j] = 0;
  }
}

// ================= main 2-sync kernel, templated on grid size =================
// NOTE: __launch_bounds__(1024, 4) for BOTH instantiations. Round 7 measured:
// (1024,8) forced VGPR 64->32 and spilled the 8-deep prefetch to scratch
// (WRITE_SIZE 4e4 -> 1.38e7 KB, 2x regression). With (1024,4) the compiler's
// natural allocation is 64 VGPR (round 6), which already fits 2 blocks/CU;
// the occupancy API below verifies before launching 512 blocks.
template<int NBLK>
__global__ __launch_bounds__(1024, 4) void knet2(
    const float* __restrict__ y_seq, const float* __restrict__ x0,
    const float* __restrict__ h0, const float* __restrict__ A,
    const float* __restrict__ Cm, const float* __restrict__ W1,
    const float* __restrict__ b1, const float* __restrict__ b_ih,
    const float* __restrict__ b_hh, const float* __restrict__ b2,
    const float* __restrict__ W3, const float* __restrict__ b3,
    float* __restrict__ out, char* __restrict__ wsb, int use_w1p)
{
  constexpr int NJQ = (870 + NBLK - 1) / NBLK;   // job slots per block (2 or 4)
  constexpr int KSP = 16 / NJQ;                  // k-split ways (8 or 4)
  constexpr int GSZ = NBLK / 8;                  // barrier group size

  const int tid  = threadIdx.x;
  const int lane = tid & 63;
  const int wav  = tid >> 6;
  const int bid  = blockIdx.x;

  unsigned* bar = (unsigned*)(wsb + O_BAR);
  float* zp  = (float*)(wsb + O_ZP);
  float* gi  = (float*)(wsb + O_GI);
  float* gh  = (float*)(wsb + O_GH);
  const unsigned short* bwih = (const unsigned short*)(wsb + O_WIH);
  const unsigned short* bwhh = (const unsigned short*)(wsb + O_WHH);
  const unsigned short* bw2  = (const unsigned short*)(wsb + O_W2B);
  const uint4* w1p = (const uint4*)(wsb + O_W1P);

  __shared__ __align__(16) uint4 s_l1u[520];     // l1 bf16
  __shared__ __align__(16) uint4 s_h4u[292];     // h bf16 (MFMA operand)
  __shared__ __align__(16) unsigned short s_h2[2336];  // h_new bf16 (C)
  __shared__ float s_part[NJQ][KSP][16];
  __shared__ __align__(16) unsigned short s_kgb[64];
  __shared__ __align__(16) float s_kgf[52];
  __shared__ float s_innov[48];
  __shared__ float s_a[192];
  __shared__ float s_l2loc[8];
  __shared__ float s_xpost[4], s_xprior[4], s_dx[4];
  __shared__ float s_sc2, s_sc4;

  unsigned ep = 0;

  for (int t = 0; t <= T_STEPS; ++t) {
    // ======== prologue: x_post(t) from z-partials(t-1) [all blocks] ========
    if (t == 0) {
      if (tid < 4) s_xpost[tid] = x0[tid];
    } else {
      if (tid < 4) {
        float z = 0.f;
        for (int p = 0; p < 96; ++p) z += ld_ag_f32(&zp[p * 4 + tid]);
        float cb = 0.f;
        for (int j = 0; j < 48; ++j) cb += s_innov[j] * b3[tid * 48 + j];
        float xn = s_xprior[tid] + (z + cb) * 1e-4f;
        s_xpost[tid] = xn;
        if (bid == 0) out[tid * T_STEPS + (t - 1)] = xn;
      }
    }
    __syncthreads();
    if (t == T_STEPS) return;

    // ======== small math: x_prior, innov, kg_in ========
    if (tid < 4) {
      float xpr = 0.f;
#pragma unroll
      for (int j = 0; j < 4; j++) xpr += A[tid * 4 + j] * s_xpost[j];
      s_xprior[tid] = xpr;
    }
    __syncthreads();
    if (tid < 48) {
      float yp = Cm[tid * 5 + 4];
#pragma unroll
      for (int j = 0; j < 4; j++) yp += Cm[tid * 5 + j] * s_xprior[j];
      s_innov[tid] = y_seq[tid * T_STEPS + t] - yp;
    }
    if (tid >= 64 && tid < 68) {
      int i = tid - 64;
      s_dx[i] = s_xpost[i] - s_xprior[i];
    }
    __syncthreads();
    if (tid == 0) {
      float s2 = 0.f;
      for (int r = 0; r < 48; r++) s2 += s_innov[r] * s_innov[r];
      s_sc2 = 1.0f / fmaxf(sqrtf(s2), 1e-12f);
      float s4 = 0.f;
      for (int i = 0; i < 4; i++) s4 += s_dx[i] * s_dx[i];
      s_sc4 = 1.0f / fmaxf(sqrtf(s4), 1e-12f);
    }
    __syncthreads();
    if (tid < 64) {
      float v = (tid < 48) ? s_innov[tid] * s_sc2
              : (tid < 52) ? s_dx[tid - 48] * s_sc4 : 0.f;
      s_kgb[tid] = f2bf(v);
      if (tid < 52) s_kgf[tid] = v;
    }
    // stage h(t-1) bf16 into LDS via agent loads
    {
      const unsigned long long* hbg =
          (const unsigned long long*)(wsb + O_HB + ((t + 1) & 1) * HB_STR);
      unsigned long long* dst = (unsigned long long*)s_h4u;
      if (tid < 584) dst[tid] = ld_ag_u64(hbg + tid);
    }
    __syncthreads();

    // ======== l1 = relu(W1 @ kg + b1), redundant per block ========
    if (use_w1p) {
      const uint4* kg4 = (const uint4*)s_kgb;
      for (int r = tid; r < 4160; r += 1024) {
        const uint4* wr = w1p + (size_t)r * 7;
        float acc = b1[r];
#pragma unroll
        for (int c = 0; c < 7; c++) acc += dot8bb(wr[c], kg4[c]);
        ((unsigned short*)s_l1u)[r] = f2bf(fmaxf(acc, 0.f));
      }
    } else {
      const float4* kg4 = (const float4*)s_kgf;
      for (int r = tid; r < 4160; r += 1024) {
        const float4* wr = (const float4*)(W1 + (size_t)r * 52);
        float acc = b1[r];
#pragma unroll
        for (int c = 0; c < 13; c++) acc += dot4(wr[c], kg4[c]);
        ((unsigned short*)s_l1u)[r] = f2bf(fmaxf(acc, 0.f));
      }
    }
    __syncthreads();

    // ======== GRU GEMV via MFMA, 8-deep prefetch ========
    {
      const int q  = wav / KSP;       // job slot
      const int kw = wav % KSP;       // k-split index
      const int job = bid + NBLK * q;
      if (job < 870) {
        const int side = (job < 435) ? 0 : 1;
        const int rt   = side ? (job - 435) : job;
        const int row  = rt * 16 + (lane & 15);
        const int xoff = lane >> 4;
        const uint4* xs;
        const uint4* wp;
        int kbeg, kend;
        if (side == 0) {
          xs = s_l1u;
          wp = (const uint4*)(bwih + (size_t)row * 4160) + xoff;
          constexpr int base = 130 / KSP, rem = 130 % KSP;
          kbeg = kw * base + (kw < rem ? kw : rem);
          kend = kbeg + base + (kw < rem ? 1 : 0);
        } else {
          xs = s_h4u;
          wp = (const uint4*)(bwhh + (size_t)row * 2320) + xoff;
          constexpr int base = 73 / KSP, rem = 73 % KSP;
          kbeg = kw * base + (kw < rem ? kw : rem);
          kend = kbeg + base + (kw < rem ? 1 : 0);
        }
        f32x4 acc = {0.f, 0.f, 0.f, 0.f};
        uint4 b0 = wp[(size_t)(kbeg + 0) * 4];
        uint4 b1r = wp[(size_t)(kbeg + 1) * 4];
        uint4 b2r = wp[(size_t)(kbeg + 2) * 4];
        uint4 b3r = wp[(size_t)(kbeg + 3) * 4];
        uint4 b4 = wp[(size_t)(kbeg + 4) * 4];
        uint4 b5 = wp[(size_t)(kbeg + 5) * 4];
        uint4 b6 = wp[(size_t)(kbeg + 6) * 4];
        uint4 b7 = wp[(size_t)(kbeg + 7) * 4];
        int kt = kbeg;
#define GSTEP(P, B) { acc = __builtin_amdgcn_mfma_f32_16x16x32_bf16( \
            __builtin_bit_cast(bf16x8, B), \
            __builtin_bit_cast(bf16x8, xs[(kt + P) * 4 + xoff]), acc, 0, 0, 0); \
            B = wp[(size_t)(kt + 8 + P) * 4]; }
        while (kt + 8 <= kend) {
          GSTEP(0, b0) GSTEP(1, b1r) GSTEP(2, b2r) GSTEP(3, b3r)
          GSTEP(4, b4) GSTEP(5, b5) GSTEP(6, b6) GSTEP(7, b7)
          kt += 8;
        }
#undef GSTEP
#define TSTEP(P, B) if (kt + P < kend) acc = __builtin_amdgcn_mfma_f32_16x16x32_bf16( \
            __builtin_bit_cast(bf16x8, B), \
            __builtin_bit_cast(bf16x8, xs[(kt + P) * 4 + xoff]), acc, 0, 0, 0);
        TSTEP(0, b0) TSTEP(1, b1r) TSTEP(2, b2r) TSTEP(3, b3r)
        TSTEP(4, b4) TSTEP(5, b5) TSTEP(6, b6) TSTEP(7, b7)
#undef TSTEP
        if ((lane & 15) == 0) {
          int rb = (lane >> 4) * 4;
#pragma unroll
          for (int i = 0; i < 4; i++) s_part[q][kw][rb + i] = acc[i];
        }
      }
    }
    __syncthreads();
    if (tid < NJQ * 16) {
      int q = tid >> 4, r = tid & 15;
      int job = bid + NBLK * q;
      if (job < 870) {
        float s = 0.f;
#pragma unroll
        for (int k = 0; k < KSP; k++) s += s_part[q][k][r];
        if (job < 435) st_ag_f32(&gi[job * 16 + r], s);
        else st_ag_f32(&gh[(job - 435) * 16 + r], s);
      }
    }
    ++ep; gbar<GSZ>(bar, bid, ep);   // -------- SYNC 1: gi/gh ready --------

    // ======== C: gates (96 blocks, redundant), l2, z-partials ========
    if (bid < 96) {
      float* hf_out = (float*)(wsb + O_HF + (t & 1) * HF_STR);
      unsigned* hb_out32 = (unsigned*)(wsb + O_HB + (t & 1) * HB_STR);
      const float* hf_old = (const float*)(wsb + O_HF + ((t + 1) & 1) * HF_STR);
      for (int j = tid; j < 2320; j += 1024) {
        float ir = ld_ag_f32(&gi[j]) + b_ih[j];
        float iz = ld_ag_f32(&gi[2320 + j]) + b_ih[2320 + j];
        float ig = ld_ag_f32(&gi[4640 + j]) + b_ih[4640 + j];
        float hr = ld_ag_f32(&gh[j]) + b_hh[j];
        float hz = ld_ag_f32(&gh[2320 + j]) + b_hh[2320 + j];
        float hg = ld_ag_f32(&gh[4640 + j]) + b_hh[4640 + j];
        float rr = 1.f / (1.f + expf(-(ir + hr)));
        float zz = 1.f / (1.f + expf(-(iz + hz)));
        float gg = tanhf(ig + rr * hg);
        float hold = (t == 0) ? h0[j] : ld_ag_f32(&hf_old[j]);
        float hn = (1.f - zz) * gg + zz * hold;
        s_h2[j] = f2bf(hn);
        if (bid == 0) st_ag_f32(&hf_out[j], hn);
      }
      if (tid < 16) s_h2[2320 + tid] = 0;   // keep K-pad zero
      __syncthreads();
      // publish h_new bf16 (bid 0 only), packed u32 agent stores
      if (bid == 0 && tid < 1168) {
        unsigned v = (unsigned)s_h2[2 * tid] | ((unsigned)s_h2[2 * tid + 1] << 16);
        st_ag_u32(hb_out32 + tid, v);
      }
      // l2 rows (8 per block), bf16 VALU dot from LDS
      if (wav < 8) {
        const int row = bid * 8 + wav;
        const uint4* wr = (const uint4*)(bw2 + (size_t)row * 2320);
        const uint4* hx = (const uint4*)s_h2;
        float acc = 0.f;
        for (int k = lane; k < 290; k += 64) acc += dot8bb(wr[k], hx[k]);
        acc = wred(acc);
        if (lane == 0) s_l2loc[wav] = fmaxf(acc + b2[row], 0.f);
      }
      __syncthreads();
      // z-partials
      if (tid < 192) {
        const float* w3r = W3 + (size_t)tid * 768 + bid * 8;
        float a = 0.f;
#pragma unroll
        for (int r = 0; r < 8; r++) a += w3r[r] * s_l2loc[r];
        s_a[tid] = a * s_innov[tid % 48];
      }
      __syncthreads();
      if (tid < 4) {
        float zv = 0.f;
        for (int j = 0; j < 48; j++) zv += s_a[tid * 48 + j];
        st_ag_f32(&zp[bid * 4 + tid], zv);
      }
    }
    ++ep; gbar<GSZ>(bar, bid, ep);   // -------- SYNC 2: h/l2/z ready --------
  }
}

// ================= cooperative fp32 kernel (proven fallback) =================
__global__ __launch_bounds__(256, 2) void knet(
    const float* __restrict__ y_seq, const float* __restrict__ x0,
    const float* __restrict__ h0, const float* __restrict__ A,
    const float* __restrict__ Cm, const float* __restrict__ W1,
    const float* __restrict__ b1, const float* __restrict__ W_ih,
    const float* __restrict__ W_hh, const float* __restrict__ b_ih,
    const float* __restrict__ b_hh, const float* __restrict__ W2,
    const float* __restrict__ b2, const float* __restrict__ W3,
    const float* __restrict__ b3, float* __restrict__ out,
    float* __restrict__ ws)
{
  cg::grid_group grid = cg::this_grid();
  const int tid = threadIdx.x, lane = tid & 63, wav = tid >> 6, bid = blockIdx.x;
  const int gt = bid * 256 + tid, wave_g = bid * 4 + wav, NW = gridDim.x * 4;

  __shared__ __align__(16) float4 s_buf4[1040];
  __shared__ __align__(16) float4 s_h4[580];
  __shared__ __align__(16) float s_kgin[52];
  __shared__ float s_innov[48];
  __shared__ float s_xpost[4], s_xprior[4], s_dx[4];
  __shared__ float s_sc2, s_sc4;

  for (int t = 0; t <= T_STEPS; ++t) {
    if (t == 0) {
      if (tid < 4) s_xpost[tid] = x0[tid];
    } else {
      const float4* vv  = (const float4*)(ws + WS_V + wav * 768);
      const float4* l2v = (const float4*)(ws + WS_L2);
      float acc = 0.f;
      for (int k = lane; k < 192; k += 64) acc += dot4(vv[k], l2v[k]);
      acc = wred(acc);
      if (lane == 0)
        s_xpost[wav] = s_xprior[wav] + (acc + ws[WS_C + wav]) * 1e-4f;
    }
    __syncthreads();
    if (bid == 0 && t > 0 && tid < 4) out[tid * T_STEPS + (t - 1)] = s_xpost[tid];
    if (t == T_STEPS) return;

    if (tid < 4) {
      float xp = 0.f;
#pragma unroll
      for (int j = 0; j < 4; j++) xp += A[tid * 4 + j] * s_xpost[j];
      s_xprior[tid] = xp;
    }
    __syncthreads();
    if (tid < 48) {
      float yp = Cm[tid * 5 + 4];
#pragma unroll
      for (int j = 0; j < 4; j++) yp += Cm[tid * 5 + j] * s_xprior[j];
      s_innov[tid] = y_seq[tid * T_STEPS + t] - yp;
    }
    if (tid >= 64 && tid < 68) {
      int i = tid - 64;
      s_dx[i] = s_xpost[i] - s_xprior[i];
    }
    __syncthreads();
    if (tid == 0) {
      float s2 = 0.f;
      for (int r = 0; r < 48; r++) s2 += s_innov[r] * s_innov[r];
      s_sc2 = 1.0f / fmaxf(sqrtf(s2), 1e-12f);
      float s4 = 0.f;
      for (int i = 0; i < 4; i++) s4 += s_dx[i] * s_dx[i];
      s_sc4 = 1.0f / fmaxf(sqrtf(s4), 1e-12f);
    }
    __syncthreads();
    if (tid < 48) s_kgin[tid] = s_innov[tid] * s_sc2;
    else if (tid < 52) s_kgin[tid] = s_dx[tid - 48] * s_sc4;
    __syncthreads();

    if (gt < 4160) {
      const float4* wr  = (const float4*)(W1 + (size_t)gt * 52);
      const float4* kg4 = (const float4*)s_kgin;
      float acc = b1[gt];
#pragma unroll
      for (int k = 0; k < 13; k++) acc += dot4(wr[k], kg4[k]);
      ws[WS_L1 + gt] = fmaxf(acc, 0.f);
    }
    grid.sync();

    {
      const float* h_old = (t == 0) ? h0 : (ws + (((t & 1) == 0) ? WS_H0 : WS_H1));
      float* h_new = ws + (((t & 1) == 0) ? WS_H1 : WS_H0);
      const float4* l1g = (const float4*)(ws + WS_L1);
      for (int i = tid; i < 1040; i += 256) s_buf4[i] = l1g[i];
      const float4* hog = (const float4*)h_old;
      for (int i = tid; i < 580; i += 256) s_h4[i] = hog[i];
      __syncthreads();
      const float* s_h = (const float*)s_h4;

      for (int j = wave_g; j < 2320; j += NW) {
        const float4* r0 = (const float4*)(W_ih + (size_t)j * 4160);
        const float4* r1 = (const float4*)(W_ih + (size_t)(j + 2320) * 4160);
        const float4* r2 = (const float4*)(W_ih + (size_t)(j + 4640) * 4160);
        float a0 = 0.f, a1 = 0.f, a2 = 0.f;
#pragma unroll 4
        for (int k = lane; k < 1040; k += 64) {
          float4 x = s_buf4[k];
          a0 += dot4(r0[k], x); a1 += dot4(r1[k], x); a2 += dot4(r2[k], x);
        }
        const float4* q0 = (const float4*)(W_hh + (size_t)j * 2320);
        const float4* q1 = (const float4*)(W_hh + (size_t)(j + 2320) * 2320);
        const float4* q2 = (const float4*)(W_hh + (size_t)(j + 4640) * 2320);
        float c0 = 0.f, c1 = 0.f, c2 = 0.f;
#pragma unroll 4
        for (int k = lane; k < 580; k += 64) {
          float4 x = s_h4[k];
          c0 += dot4(q0[k], x); c1 += dot4(q1[k], x); c2 += dot4(q2[k], x);
        }
        a0 = wred(a0); a1 = wred(a1); a2 = wred(a2);
        c0 = wred(c0); c1 = wred(c1); c2 = wred(c2);
        if (lane == 0) {
          float ir = a0 + b_ih[j], iz = a1 + b_ih[j + 2320], ig = a2 + b_ih[j + 4640];
          float hr = c0 + b_hh[j], hz = c1 + b_hh[j + 2320], hg = c2 + b_hh[j + 4640];
          float rr = 1.f / (1.f + expf(-(ir + hr)));
          float zz = 1.f / (1.f + expf(-(iz + hz)));
          float gg = tanhf(ig + rr * hg);
          h_new[j] = (1.f - zz) * gg + zz * s_h[j];
        }
      }
    }
    grid.sync();

    {
      const float* h_new = ws + (((t & 1) == 0) ? WS_H1 : WS_H0);
      const float4* hv = (const float4*)h_new;
      for (int i = tid; i < 580; i += 256) s_buf4[i] = hv[i];
      __syncthreads();

      if (gt < 3072) {
        int i = gt / 768, cc = gt - i * 768;
        const float* wcol = W3 + (size_t)(i * 48) * 768 + cc;
        float acc = 0.f;
#pragma unroll 8
        for (int j = 0; j < 48; j++) acc += s_innov[j] * wcol[(size_t)j * 768];
        ws[WS_V + gt] = acc;
      } else if (gt < 3076) {
        int i = gt - 3072;
        float acc = 0.f;
        for (int j = 0; j < 48; j++) acc += s_innov[j] * b3[i * 48 + j];
        ws[WS_C + i] = acc;
      }

      for (int task = wave_g; task < 768; task += NW) {
        const float4* row = (const float4*)(W2 + (size_t)task * 2320);
        float acc = 0.f;
#pragma unroll 4
        for (int k = lane; k < 580; k += 64) acc += dot4(row[k], s_buf4[k]);
        acc = wred(acc);
        if (lane == 0) ws[WS_L2 + task] = fmaxf(acc + b2[task], 0.f);
      }
    }
    grid.sync();
  }
}

extern "C" void kernel_launch(void* const* d_in, const int* in_sizes, int n_in,
                              void* d_out, int out_size, void* d_ws, size_t ws_size,
                              hipStream_t stream) {
  const float* y_seq = (const float*)d_in[0];
  const float* x0    = (const float*)d_in[1];
  const float* h0    = (const float*)d_in[2];
  const float* A     = (const float*)d_in[3];
  const float* Cm    = (const float*)d_in[4];
  const float* W1    = (const float*)d_in[5];
  const float* b1    = (const float*)d_in[6];
  const float* W_ih  = (const float*)d_in[7];
  const float* W_hh  = (const float*)d_in[8];
  const float* b_ih  = (const float*)d_in[9];
  const float* b_hh  = (const float*)d_in[10];
  const float* W2    = (const float*)d_in[11];
  const float* b2    = (const float*)d_in[12];
  const float* W3    = (const float*)d_in[13];
  const float* b3    = (const float*)d_in[14];
  float* out = (float*)d_out;
  float* ws  = (float*)d_ws;
  char* wsb  = (char*)d_ws;

  if (ws_size >= NEED_MIN) {
    int use_w1p = (ws_size >= NEED_FULL) ? 1 : 0;
    hipMemsetAsync(wsb + O_BAR, 0, 256, stream);
    k_cvt<<<1024, 256, 0, stream>>>((const float4*)W_ih,
                                    (ushort4*)(wsb + O_WIH), N_IH / 4);
    k_cvt<<<1024, 256, 0, stream>>>((const float4*)W_hh,
                                    (ushort4*)(wsb + O_WHH), N_HH / 4);
    k_cvt<<<512, 256, 0, stream>>>((const float4*)W2,
                                   (ushort4*)(wsb + O_W2B), N_W2 / 4);
    if (use_w1p)
      k_cvtw1<<<(4160 * 56 + 255) / 256, 256, 0, stream>>>(
          W1, (unsigned short*)(wsb + O_W1P));
    k_h0<<<10, 256, 0, stream>>>(h0, (unsigned short*)(wsb + O_HB),
                                 (unsigned short*)(wsb + O_HB + HB_STR));

    void* args[] = { &y_seq, &x0, &h0, &A, &Cm, &W1, &b1, &b_ih, &b_hh,
                     &b2, &W3, &b3, &out, &wsb, &use_w1p };

    // 2 blocks/CU only if it fits at the compiler's NATURAL register count
    int nb512 = 0;
    hipError_t oe = hipOccupancyMaxActiveBlocksPerMultiprocessor(
        &nb512, (const void*)knet2<512>, 1024, 0);
    if (oe == hipSuccess && nb512 >= 2) {
      hipError_t err = hipLaunchCooperativeKernel(
          reinterpret_cast<void*>(knet2<512>), dim3(512), dim3(1024), args, 0, stream);
      if (err == hipSuccess) return;
    }
    // round-6-proven config
    int nb256 = 0;
    oe = hipOccupancyMaxActiveBlocksPerMultiprocessor(
        &nb256, (const void*)knet2<256>, 1024, 0);
    if (oe == hipSuccess && nb256 >= 1) {
      hipError_t err = hipLaunchCooperativeKernel(
          reinterpret_cast<void*>(knet2<256>), dim3(256), dim3(1024), args, 0, stream);
      if (err == hipSuccess) return;
    }
  }

  {
    int nb = 0;
    hipError_t oe = hipOccupancyMaxActiveBlocksPerMultiprocessor(
        &nb, (const void*)knet, 256, 0);
    int bpc = (oe == hipSuccess && nb >= 1) ? (nb > 1 ? 1 : nb) : 1;
    void* args[] = { &y_seq, &x0, &h0, &A, &Cm, &W1, &b1, &W_ih, &W_hh,
                     &b_ih, &b_hh, &W2, &b2, &W3, &b3, &out, &ws };
    hipLaunchCooperativeKernel(
        reinterpret_cast<void*>(knet), dim3(256 * bpc), dim3(256), args, 0, stream);
  }
}

// Round 9
// 36233.511 us; speedup vs baseline: 1.0030x; 1.0030x over previous
//
#include <hip/hip_runtime.h>
#include <hip/hip_cooperative_groups.h>

namespace cg = cooperative_groups;

#define T_STEPS 256
// sizes: M=4 N=48 H1=4160 HID=2320 3HID=6960 H2=768 OUT=192 KGIN=52

// ---------------- ws byte-offset layout ----------------
#define O_BAR   0                  // 10 u32 barrier state (memset each launch)
#define O_ZP    256                // 96*4 f32 z-partials
#define O_HF    2048               // 2 x 2320 f32 (h state, parity)
#define HF_STR  9280
#define O_HB    20608              // 2 x 2336 bf16 (h state bf16, parity)
#define HB_STR  4672
#define O_GI    30208              // 6960 f32
#define O_GH    58048              // 6960 f32
#define O_WIH   86016              // 6960*4160 bf16
#define O_WHH   57993216           // 6960*2320 bf16
#define O_W2B   90287616           // 768*2320 bf16
#define NEED_MIN 93851136
#define O_W1P   93851136           // 4160*56 bf16 (padded W1)
#define NEED_FULL 94317056

#define N_IH  28953600
#define N_HH  16147200
#define N_W2  1781760

// legacy fp32-path offsets (float units) for fallback kernel
#define WS_L1  0
#define WS_H0  4160
#define WS_H1  6480
#define WS_L2  8800
#define WS_V   9568
#define WS_C   12640

typedef __attribute__((ext_vector_type(8))) short bf16x8;
typedef __attribute__((ext_vector_type(4))) float f32x4;

__device__ __forceinline__ float wred(float v) {
#pragma unroll
  for (int m = 32; m; m >>= 1) v += __shfl_xor(v, m, 64);
  return v;
}
__device__ __forceinline__ float dot4(float4 a, float4 b) {
  return a.x * b.x + a.y * b.y + a.z * b.z + a.w * b.w;
}
__device__ __forceinline__ float blo(unsigned u) {
  unsigned t = u << 16; return __builtin_bit_cast(float, t);
}
__device__ __forceinline__ float bhi(unsigned u) {
  unsigned t = u & 0xFFFF0000u; return __builtin_bit_cast(float, t);
}
__device__ __forceinline__ float dot8bb(uint4 w, uint4 x) {
  float s;
  s  = blo(w.x) * blo(x.x) + bhi(w.x) * bhi(x.x);
  s += blo(w.y) * blo(x.y) + bhi(w.y) * bhi(x.y);
  s += blo(w.z) * blo(x.z) + bhi(w.z) * bhi(x.z);
  s += blo(w.w) * blo(x.w) + bhi(w.w) * bhi(x.w);
  return s;
}
__device__ __forceinline__ unsigned short f2bf(float f) {  // RNE
  unsigned u = __builtin_bit_cast(unsigned, f);
  unsigned r = u + 0x7FFF + ((u >> 16) & 1);
  return (unsigned short)(r >> 16);
}

// ---- scoped accessors: cross-block data via coherence point, no invalidates
__device__ __forceinline__ void st_ag_f32(float* p, float v) {
  __hip_atomic_store(p, v, __ATOMIC_RELAXED, __HIP_MEMORY_SCOPE_AGENT);
}
__device__ __forceinline__ float ld_ag_f32(const float* p) {
  return __hip_atomic_load(p, __ATOMIC_RELAXED, __HIP_MEMORY_SCOPE_AGENT);
}
__device__ __forceinline__ void st_ag_u32(unsigned* p, unsigned v) {
  __hip_atomic_store(p, v, __ATOMIC_RELAXED, __HIP_MEMORY_SCOPE_AGENT);
}
__device__ __forceinline__ unsigned long long ld_ag_u64(const unsigned long long* p) {
  return __hip_atomic_load(p, __ATOMIC_RELAXED, __HIP_MEMORY_SCOPE_AGENT);
}

// ---------- two-level grid barrier: release-arrive, RELAXED polls ----------
template<int GSZ>
__device__ __forceinline__ void gbar(unsigned* bar, int bid, unsigned target) {
  __syncthreads();
  if (threadIdx.x == 0) {
    unsigned* grp   = bar + (bid & 7);
    unsigned* lead  = bar + 8;
    unsigned* epoch = bar + 9;
    unsigned old = __hip_atomic_fetch_add(grp, 1u, __ATOMIC_RELEASE, __HIP_MEMORY_SCOPE_AGENT);
    if (old == (unsigned)(GSZ - 1)) {
      __hip_atomic_store(grp, 0u, __ATOMIC_RELAXED, __HIP_MEMORY_SCOPE_AGENT);
      unsigned lo = __hip_atomic_fetch_add(lead, 1u, __ATOMIC_ACQ_REL, __HIP_MEMORY_SCOPE_AGENT);
      if (lo == 7u) {
        __hip_atomic_store(lead, 0u, __ATOMIC_RELAXED, __HIP_MEMORY_SCOPE_AGENT);
        __hip_atomic_store(epoch, target, __ATOMIC_RELEASE, __HIP_MEMORY_SCOPE_AGENT);
      } else {
        while (__hip_atomic_load(epoch, __ATOMIC_RELAXED, __HIP_MEMORY_SCOPE_AGENT) < target)
          __builtin_amdgcn_s_sleep(1);
      }
    } else {
      while (__hip_atomic_load(epoch, __ATOMIC_RELAXED, __HIP_MEMORY_SCOPE_AGENT) < target)
        __builtin_amdgcn_s_sleep(1);
    }
  }
  __syncthreads();
}

// ---------------- pre-pass conversion kernels ----------------
__global__ __launch_bounds__(256) void k_cvt(const float4* __restrict__ src,
                                             ushort4* __restrict__ dst, int n4) {
  int i = blockIdx.x * 256 + threadIdx.x, st = gridDim.x * 256;
  for (; i < n4; i += st) {
    float4 v = src[i];
    ushort4 o;
    o.x = f2bf(v.x); o.y = f2bf(v.y); o.z = f2bf(v.z); o.w = f2bf(v.w);
    dst[i] = o;
  }
}
__global__ __launch_bounds__(256) void k_cvtw1(const float* __restrict__ W1,
                                               unsigned short* __restrict__ dst) {
  int i = blockIdx.x * 256 + threadIdx.x;           // over 4160*56
  if (i < 4160 * 56) {
    int r = i / 56, c = i - r * 56;
    dst[i] = (c < 52) ? f2bf(W1[r * 52 + c]) : (unsigned short)0;
  }
}
__global__ __launch_bounds__(256) void k_h0(const float* __restrict__ h0,
                                            unsigned short* __restrict__ hb0,
                                            unsigned short* __restrict__ hb1) {
  int j = blockIdx.x * 256 + threadIdx.x;
  if (j < 2336) {
    hb1[j] = (j < 2320) ? f2bf(h0[j]) : (unsigned short)0;
    if (j >= 2320) hb0[j] = 0;
  }
}

// ================= main 2-sync kernel (256 blocks x 1024 threads) =================
// Round-8 forensics: knet2<512> launched (absmax changed), did NOT co-reside
// (occupancy 49.8%), and time-shared at 2x cost -> 512-block coop is dead.
// This round: keep the proven 256-block config, deepen the GEMV prefetch 8->16
// to double per-wave outstanding loads (latency-bound L3 stream, R6 model).
// __launch_bounds__(1024,4) caps VGPR at 128; 16 uint4 buffers = 64 VGPR,
// natural total ~100-110 -> no spill (WRITE_SIZE is the guard metric).
template<int NBLK>
__global__ __launch_bounds__(1024, 4) void knet2(
    const float* __restrict__ y_seq, const float* __restrict__ x0,
    const float* __restrict__ h0, const float* __restrict__ A,
    const float* __restrict__ Cm, const float* __restrict__ W1,
    const float* __restrict__ b1, const float* __restrict__ b_ih,
    const float* __restrict__ b_hh, const float* __restrict__ b2,
    const float* __restrict__ W3, const float* __restrict__ b3,
    float* __restrict__ out, char* __restrict__ wsb, int use_w1p)
{
  constexpr int NJQ = (870 + NBLK - 1) / NBLK;   // job slots per block (4)
  constexpr int KSP = 16 / NJQ;                  // k-split ways (4)
  constexpr int GSZ = NBLK / 8;                  // barrier group size

  const int tid  = threadIdx.x;
  const int lane = tid & 63;
  const int wav  = tid >> 6;
  const int bid  = blockIdx.x;

  unsigned* bar = (unsigned*)(wsb + O_BAR);
  float* zp  = (float*)(wsb + O_ZP);
  float* gi  = (float*)(wsb + O_GI);
  float* gh  = (float*)(wsb + O_GH);
  const unsigned short* bwih = (const unsigned short*)(wsb + O_WIH);
  const unsigned short* bwhh = (const unsigned short*)(wsb + O_WHH);
  const unsigned short* bw2  = (const unsigned short*)(wsb + O_W2B);
  const uint4* w1p = (const uint4*)(wsb + O_W1P);

  __shared__ __align__(16) uint4 s_l1u[520];     // l1 bf16
  __shared__ __align__(16) uint4 s_h4u[292];     // h bf16 (MFMA operand)
  __shared__ __align__(16) unsigned short s_h2[2336];  // h_new bf16 (C)
  __shared__ float s_part[NJQ][KSP][16];
  __shared__ __align__(16) unsigned short s_kgb[64];
  __shared__ __align__(16) float s_kgf[52];
  __shared__ float s_innov[48];
  __shared__ float s_a[192];
  __shared__ float s_l2loc[8];
  __shared__ float s_xpost[4], s_xprior[4], s_dx[4];
  __shared__ float s_sc2, s_sc4;

  unsigned ep = 0;

  for (int t = 0; t <= T_STEPS; ++t) {
    // ======== prologue: x_post(t) from z-partials(t-1) [all blocks] ========
    if (t == 0) {
      if (tid < 4) s_xpost[tid] = x0[tid];
    } else {
      if (tid < 4) {
        float z = 0.f;
        for (int p = 0; p < 96; ++p) z += ld_ag_f32(&zp[p * 4 + tid]);
        float cb = 0.f;
        for (int j = 0; j < 48; ++j) cb += s_innov[j] * b3[tid * 48 + j];
        float xn = s_xprior[tid] + (z + cb) * 1e-4f;
        s_xpost[tid] = xn;
        if (bid == 0) out[tid * T_STEPS + (t - 1)] = xn;
      }
    }
    __syncthreads();
    if (t == T_STEPS) return;

    // ======== small math: x_prior, innov, kg_in ========
    if (tid < 4) {
      float xpr = 0.f;
#pragma unroll
      for (int j = 0; j < 4; j++) xpr += A[tid * 4 + j] * s_xpost[j];
      s_xprior[tid] = xpr;
    }
    __syncthreads();
    if (tid < 48) {
      float yp = Cm[tid * 5 + 4];
#pragma unroll
      for (int j = 0; j < 4; j++) yp += Cm[tid * 5 + j] * s_xprior[j];
      s_innov[tid] = y_seq[tid * T_STEPS + t] - yp;
    }
    if (tid >= 64 && tid < 68) {
      int i = tid - 64;
      s_dx[i] = s_xpost[i] - s_xprior[i];
    }
    __syncthreads();
    if (tid == 0) {
      float s2 = 0.f;
      for (int r = 0; r < 48; r++) s2 += s_innov[r] * s_innov[r];
      s_sc2 = 1.0f / fmaxf(sqrtf(s2), 1e-12f);
      float s4 = 0.f;
      for (int i = 0; i < 4; i++) s4 += s_dx[i] * s_dx[i];
      s_sc4 = 1.0f / fmaxf(sqrtf(s4), 1e-12f);
    }
    __syncthreads();
    if (tid < 64) {
      float v = (tid < 48) ? s_innov[tid] * s_sc2
              : (tid < 52) ? s_dx[tid - 48] * s_sc4 : 0.f;
      s_kgb[tid] = f2bf(v);
      if (tid < 52) s_kgf[tid] = v;
    }
    // stage h(t-1) bf16 into LDS via agent loads
    {
      const unsigned long long* hbg =
          (const unsigned long long*)(wsb + O_HB + ((t + 1) & 1) * HB_STR);
      unsigned long long* dst = (unsigned long long*)s_h4u;
      if (tid < 584) dst[tid] = ld_ag_u64(hbg + tid);
    }
    __syncthreads();

    // ======== l1 = relu(W1 @ kg + b1), redundant per block ========
    if (use_w1p) {
      const uint4* kg4 = (const uint4*)s_kgb;
      for (int r = tid; r < 4160; r += 1024) {
        const uint4* wr = w1p + (size_t)r * 7;
        float acc = b1[r];
#pragma unroll
        for (int c = 0; c < 7; c++) acc += dot8bb(wr[c], kg4[c]);
        ((unsigned short*)s_l1u)[r] = f2bf(fmaxf(acc, 0.f));
      }
    } else {
      const float4* kg4 = (const float4*)s_kgf;
      for (int r = tid; r < 4160; r += 1024) {
        const float4* wr = (const float4*)(W1 + (size_t)r * 52);
        float acc = b1[r];
#pragma unroll
        for (int c = 0; c < 13; c++) acc += dot4(wr[c], kg4[c]);
        ((unsigned short*)s_l1u)[r] = f2bf(fmaxf(acc, 0.f));
      }
    }
    __syncthreads();

    // ======== GRU GEMV via MFMA, 16-deep prefetch ========
    {
      const int q  = wav / KSP;       // job slot
      const int kw = wav % KSP;       // k-split index
      const int job = bid + NBLK * q;
      if (job < 870) {
        const int side = (job < 435) ? 0 : 1;
        const int rt   = side ? (job - 435) : job;
        const int row  = rt * 16 + (lane & 15);
        const int xoff = lane >> 4;
        const uint4* xs;
        const uint4* wp;
        int kbeg, kend;
        if (side == 0) {
          xs = s_l1u;
          wp = (const uint4*)(bwih + (size_t)row * 4160) + xoff;
          constexpr int base = 130 / KSP, rem = 130 % KSP;
          kbeg = kw * base + (kw < rem ? kw : rem);
          kend = kbeg + base + (kw < rem ? 1 : 0);
        } else {
          xs = s_h4u;
          wp = (const uint4*)(bwhh + (size_t)row * 2320) + xoff;
          constexpr int base = 73 / KSP, rem = 73 % KSP;
          kbeg = kw * base + (kw < rem ? kw : rem);
          kend = kbeg + base + (kw < rem ? 1 : 0);
        }
        f32x4 acc = {0.f, 0.f, 0.f, 0.f};
        uint4 b0  = wp[(size_t)(kbeg + 0) * 4];
        uint4 b1r = wp[(size_t)(kbeg + 1) * 4];
        uint4 b2r = wp[(size_t)(kbeg + 2) * 4];
        uint4 b3r = wp[(size_t)(kbeg + 3) * 4];
        uint4 b4  = wp[(size_t)(kbeg + 4) * 4];
        uint4 b5  = wp[(size_t)(kbeg + 5) * 4];
        uint4 b6  = wp[(size_t)(kbeg + 6) * 4];
        uint4 b7  = wp[(size_t)(kbeg + 7) * 4];
        uint4 b8  = wp[(size_t)(kbeg + 8) * 4];
        uint4 b9  = wp[(size_t)(kbeg + 9) * 4];
        uint4 b10 = wp[(size_t)(kbeg + 10) * 4];
        uint4 b11 = wp[(size_t)(kbeg + 11) * 4];
        uint4 b12 = wp[(size_t)(kbeg + 12) * 4];
        uint4 b13 = wp[(size_t)(kbeg + 13) * 4];
        uint4 b14 = wp[(size_t)(kbeg + 14) * 4];
        uint4 b15 = wp[(size_t)(kbeg + 15) * 4];
        int kt = kbeg;
#define GSTEP(P, B) { acc = __builtin_amdgcn_mfma_f32_16x16x32_bf16( \
            __builtin_bit_cast(bf16x8, B), \
            __builtin_bit_cast(bf16x8, xs[(kt + P) * 4 + xoff]), acc, 0, 0, 0); \
            B = wp[(size_t)(kt + 16 + P) * 4]; }
        while (kt + 16 <= kend) {
          GSTEP(0, b0)  GSTEP(1, b1r)  GSTEP(2, b2r)  GSTEP(3, b3r)
          GSTEP(4, b4)  GSTEP(5, b5)   GSTEP(6, b6)   GSTEP(7, b7)
          GSTEP(8, b8)  GSTEP(9, b9)   GSTEP(10, b10) GSTEP(11, b11)
          GSTEP(12, b12) GSTEP(13, b13) GSTEP(14, b14) GSTEP(15, b15)
          kt += 16;
        }
#undef GSTEP
#define TSTEP(P, B) if (kt + P < kend) acc = __builtin_amdgcn_mfma_f32_16x16x32_bf16( \
            __builtin_bit_cast(bf16x8, B), \
            __builtin_bit_cast(bf16x8, xs[(kt + P) * 4 + xoff]), acc, 0, 0, 0);
        TSTEP(0, b0)  TSTEP(1, b1r)  TSTEP(2, b2r)  TSTEP(3, b3r)
        TSTEP(4, b4)  TSTEP(5, b5)   TSTEP(6, b6)   TSTEP(7, b7)
        TSTEP(8, b8)  TSTEP(9, b9)   TSTEP(10, b10) TSTEP(11, b11)
        TSTEP(12, b12) TSTEP(13, b13) TSTEP(14, b14) TSTEP(15, b15)
#undef TSTEP
        if ((lane & 15) == 0) {
          int rb = (lane >> 4) * 4;
#pragma unroll
          for (int i = 0; i < 4; i++) s_part[q][kw][rb + i] = acc[i];
        }
      }
    }
    __syncthreads();
    if (tid < NJQ * 16) {
      int q = tid >> 4, r = tid & 15;
      int job = bid + NBLK * q;
      if (job < 870) {
        float s = 0.f;
#pragma unroll
        for (int k = 0; k < KSP; k++) s += s_part[q][k][r];
        if (job < 435) st_ag_f32(&gi[job * 16 + r], s);
        else st_ag_f32(&gh[(job - 435) * 16 + r], s);
      }
    }
    ++ep; gbar<GSZ>(bar, bid, ep);   // -------- SYNC 1: gi/gh ready --------

    // ======== C: gates (96 blocks, redundant), l2, z-partials ========
    if (bid < 96) {
      float* hf_out = (float*)(wsb + O_HF + (t & 1) * HF_STR);
      unsigned* hb_out32 = (unsigned*)(wsb + O_HB + (t & 1) * HB_STR);
      const float* hf_old = (const float*)(wsb + O_HF + ((t + 1) & 1) * HF_STR);
      for (int j = tid; j < 2320; j += 1024) {
        float ir = ld_ag_f32(&gi[j]) + b_ih[j];
        float iz = ld_ag_f32(&gi[2320 + j]) + b_ih[2320 + j];
        float ig = ld_ag_f32(&gi[4640 + j]) + b_ih[4640 + j];
        float hr = ld_ag_f32(&gh[j]) + b_hh[j];
        float hz = ld_ag_f32(&gh[2320 + j]) + b_hh[2320 + j];
        float hg = ld_ag_f32(&gh[4640 + j]) + b_hh[4640 + j];
        float rr = 1.f / (1.f + expf(-(ir + hr)));
        float zz = 1.f / (1.f + expf(-(iz + hz)));
        float gg = tanhf(ig + rr * hg);
        float hold = (t == 0) ? h0[j] : ld_ag_f32(&hf_old[j]);
        float hn = (1.f - zz) * gg + zz * hold;
        s_h2[j] = f2bf(hn);
        if (bid == 0) st_ag_f32(&hf_out[j], hn);
      }
      if (tid < 16) s_h2[2320 + tid] = 0;   // keep K-pad zero
      __syncthreads();
      // publish h_new bf16 (bid 0 only), packed u32 agent stores
      if (bid == 0 && tid < 1168) {
        unsigned v = (unsigned)s_h2[2 * tid] | ((unsigned)s_h2[2 * tid + 1] << 16);
        st_ag_u32(hb_out32 + tid, v);
      }
      // l2 rows (8 per block), bf16 VALU dot from LDS
      if (wav < 8) {
        const int row = bid * 8 + wav;
        const uint4* wr = (const uint4*)(bw2 + (size_t)row * 2320);
        const uint4* hx = (const uint4*)s_h2;
        float acc = 0.f;
        for (int k = lane; k < 290; k += 64) acc += dot8bb(wr[k], hx[k]);
        acc = wred(acc);
        if (lane == 0) s_l2loc[wav] = fmaxf(acc + b2[row], 0.f);
      }
      __syncthreads();
      // z-partials
      if (tid < 192) {
        const float* w3r = W3 + (size_t)tid * 768 + bid * 8;
        float a = 0.f;
#pragma unroll
        for (int r = 0; r < 8; r++) a += w3r[r] * s_l2loc[r];
        s_a[tid] = a * s_innov[tid % 48];
      }
      __syncthreads();
      if (tid < 4) {
        float zv = 0.f;
        for (int j = 0; j < 48; j++) zv += s_a[tid * 48 + j];
        st_ag_f32(&zp[bid * 4 + tid], zv);
      }
    }
    ++ep; gbar<GSZ>(bar, bid, ep);   // -------- SYNC 2: h/l2/z ready --------
  }
}

// ================= cooperative fp32 kernel (proven fallback) =================
__global__ __launch_bounds__(256, 2) void knet(
    const float* __restrict__ y_seq, const float* __restrict__ x0,
    const float* __restrict__ h0, const float* __restrict__ A,
    const float* __restrict__ Cm, const float* __restrict__ W1,
    const float* __restrict__ b1, const float* __restrict__ W_ih,
    const float* __restrict__ W_hh, const float* __restrict__ b_ih,
    const float* __restrict__ b_hh, const float* __restrict__ W2,
    const float* __restrict__ b2, const float* __restrict__ W3,
    const float* __restrict__ b3, float* __restrict__ out,
    float* __restrict__ ws)
{
  cg::grid_group grid = cg::this_grid();
  const int tid = threadIdx.x, lane = tid & 63, wav = tid >> 6, bid = blockIdx.x;
  const int gt = bid * 256 + tid, wave_g = bid * 4 + wav, NW = gridDim.x * 4;

  __shared__ __align__(16) float4 s_buf4[1040];
  __shared__ __align__(16) float4 s_h4[580];
  __shared__ __align__(16) float s_kgin[52];
  __shared__ float s_innov[48];
  __shared__ float s_xpost[4], s_xprior[4], s_dx[4];
  __shared__ float s_sc2, s_sc4;

  for (int t = 0; t <= T_STEPS; ++t) {
    if (t == 0) {
      if (tid < 4) s_xpost[tid] = x0[tid];
    } else {
      const float4* vv  = (const float4*)(ws + WS_V + wav * 768);
      const float4* l2v = (const float4*)(ws + WS_L2);
      float acc = 0.f;
      for (int k = lane; k < 192; k += 64) acc += dot4(vv[k], l2v[k]);
      acc = wred(acc);
      if (lane == 0)
        s_xpost[wav] = s_xprior[wav] + (acc + ws[WS_C + wav]) * 1e-4f;
    }
    __syncthreads();
    if (bid == 0 && t > 0 && tid < 4) out[tid * T_STEPS + (t - 1)] = s_xpost[tid];
    if (t == T_STEPS) return;

    if (tid < 4) {
      float xp = 0.f;
#pragma unroll
      for (int j = 0; j < 4; j++) xp += A[tid * 4 + j] * s_xpost[j];
      s_xprior[tid] = xp;
    }
    __syncthreads();
    if (tid < 48) {
      float yp = Cm[tid * 5 + 4];
#pragma unroll
      for (int j = 0; j < 4; j++) yp += Cm[tid * 5 + j] * s_xprior[j];
      s_innov[tid] = y_seq[tid * T_STEPS + t] - yp;
    }
    if (tid >= 64 && tid < 68) {
      int i = tid - 64;
      s_dx[i] = s_xpost[i] - s_xprior[i];
    }
    __syncthreads();
    if (tid == 0) {
      float s2 = 0.f;
      for (int r = 0; r < 48; r++) s2 += s_innov[r] * s_innov[r];
      s_sc2 = 1.0f / fmaxf(sqrtf(s2), 1e-12f);
      float s4 = 0.f;
      for (int i = 0; i < 4; i++) s4 += s_dx[i] * s_dx[i];
      s_sc4 = 1.0f / fmaxf(sqrtf(s4), 1e-12f);
    }
    __syncthreads();
    if (tid < 48) s_kgin[tid] = s_innov[tid] * s_sc2;
    else if (tid < 52) s_kgin[tid] = s_dx[tid - 48] * s_sc4;
    __syncthreads();

    if (gt < 4160) {
      const float4* wr  = (const float4*)(W1 + (size_t)gt * 52);
      const float4* kg4 = (const float4*)s_kgin;
      float acc = b1[gt];
#pragma unroll
      for (int k = 0; k < 13; k++) acc += dot4(wr[k], kg4[k]);
      ws[WS_L1 + gt] = fmaxf(acc, 0.f);
    }
    grid.sync();

    {
      const float* h_old = (t == 0) ? h0 : (ws + (((t & 1) == 0) ? WS_H0 : WS_H1));
      float* h_new = ws + (((t & 1) == 0) ? WS_H1 : WS_H0);
      const float4* l1g = (const float4*)(ws + WS_L1);
      for (int i = tid; i < 1040; i += 256) s_buf4[i] = l1g[i];
      const float4* hog = (const float4*)h_old;
      for (int i = tid; i < 580; i += 256) s_h4[i] = hog[i];
      __syncthreads();
      const float* s_h = (const float*)s_h4;

      for (int j = wave_g; j < 2320; j += NW) {
        const float4* r0 = (const float4*)(W_ih + (size_t)j * 4160);
        const float4* r1 = (const float4*)(W_ih + (size_t)(j + 2320) * 4160);
        const float4* r2 = (const float4*)(W_ih + (size_t)(j + 4640) * 4160);
        float a0 = 0.f, a1 = 0.f, a2 = 0.f;
#pragma unroll 4
        for (int k = lane; k < 1040; k += 64) {
          float4 x = s_buf4[k];
          a0 += dot4(r0[k], x); a1 += dot4(r1[k], x); a2 += dot4(r2[k], x);
        }
        const float4* q0 = (const float4*)(W_hh + (size_t)j * 2320);
        const float4* q1 = (const float4*)(W_hh + (size_t)(j + 2320) * 2320);
        const float4* q2 = (const float4*)(W_hh + (size_t)(j + 4640) * 2320);
        float c0 = 0.f, c1 = 0.f, c2 = 0.f;
#pragma unroll 4
        for (int k = lane; k < 580; k += 64) {
          float4 x = s_h4[k];
          c0 += dot4(q0[k], x); c1 += dot4(q1[k], x); c2 += dot4(q2[k], x);
        }
        a0 = wred(a0); a1 = wred(a1); a2 = wred(a2);
        c0 = wred(c0); c1 = wred(c1); c2 = wred(c2);
        if (lane == 0) {
          float ir = a0 + b_ih[j], iz = a1 + b_ih[j + 2320], ig = a2 + b_ih[j + 4640];
          float hr = c0 + b_hh[j], hz = c1 + b_hh[j + 2320], hg = c2 + b_hh[j + 4640];
          float rr = 1.f / (1.f + expf(-(ir + hr)));
          float zz = 1.f / (1.f + expf(-(iz + hz)));
          float gg = tanhf(ig + rr * hg);
          h_new[j] = (1.f - zz) * gg + zz * s_h[j];
        }
      }
    }
    grid.sync();

    {
      const float* h_new = ws + (((t & 1) == 0) ? WS_H1 : WS_H0);
      const float4* hv = (const float4*)h_new;
      for (int i = tid; i < 580; i += 256) s_buf4[i] = hv[i];
      __syncthreads();

      if (gt < 3072) {
        int i = gt / 768, cc = gt - i * 768;
        const float* wcol = W3 + (size_t)(i * 48) * 768 + cc;
        float acc = 0.f;
#pragma unroll 8
        for (int j = 0; j < 48; j++) acc += s_innov[j] * wcol[(size_t)j * 768];
        ws[WS_V + gt] = acc;
      } else if (gt < 3076) {
        int i = gt - 3072;
        float acc = 0.f;
        for (int j = 0; j < 48; j++) acc += s_innov[j] * b3[i * 48 + j];
        ws[WS_C + i] = acc;
      }

      for (int task = wave_g; task < 768; task += NW) {
        const float4* row = (const float4*)(W2 + (size_t)task * 2320);
        float acc = 0.f;
#pragma unroll 4
        for (int k = lane; k < 580; k += 64) acc += dot4(row[k], s_buf4[k]);
        acc = wred(acc);
        if (lane == 0) ws[WS_L2 + task] = fmaxf(acc + b2[task], 0.f);
      }
    }
    grid.sync();
  }
}

extern "C" void kernel_launch(void* const* d_in, const int* in_sizes, int n_in,
                              void* d_out, int out_size, void* d_ws, size_t ws_size,
                              hipStream_t stream) {
  const float* y_seq = (const float*)d_in[0];
  const float* x0    = (const float*)d_in[1];
  const float* h0    = (const float*)d_in[2];
  const float* A     = (const float*)d_in[3];
  const float* Cm    = (const float*)d_in[4];
  const float* W1    = (const float*)d_in[5];
  const float* b1    = (const float*)d_in[6];
  const float* W_ih  = (const float*)d_in[7];
  const float* W_hh  = (const float*)d_in[8];
  const float* b_ih  = (const float*)d_in[9];
  const float* b_hh  = (const float*)d_in[10];
  const float* W2    = (const float*)d_in[11];
  const float* b2    = (const float*)d_in[12];
  const float* W3    = (const float*)d_in[13];
  const float* b3    = (const float*)d_in[14];
  float* out = (float*)d_out;
  float* ws  = (float*)d_ws;
  char* wsb  = (char*)d_ws;

  if (ws_size >= NEED_MIN) {
    int use_w1p = (ws_size >= NEED_FULL) ? 1 : 0;
    hipMemsetAsync(wsb + O_BAR, 0, 256, stream);
    k_cvt<<<1024, 256, 0, stream>>>((const float4*)W_ih,
                                    (ushort4*)(wsb + O_WIH), N_IH / 4);
    k_cvt<<<1024, 256, 0, stream>>>((const float4*)W_hh,
                                    (ushort4*)(wsb + O_WHH), N_HH / 4);
    k_cvt<<<512, 256, 0, stream>>>((const float4*)W2,
                                   (ushort4*)(wsb + O_W2B), N_W2 / 4);
    if (use_w1p)
      k_cvtw1<<<(4160 * 56 + 255) / 256, 256, 0, stream>>>(
          W1, (unsigned short*)(wsb + O_W1P));
    k_h0<<<10, 256, 0, stream>>>(h0, (unsigned short*)(wsb + O_HB),
                                 (unsigned short*)(wsb + O_HB + HB_STR));

    void* args[] = { &y_seq, &x0, &h0, &A, &Cm, &W1, &b1, &b_ih, &b_hh,
                     &b2, &W3, &b3, &out, &wsb, &use_w1p };

    // 256 blocks x 1024 threads ONLY (round 8 proved 512-block coop time-shares)
    int nb256 = 0;
    hipError_t oe = hipOccupancyMaxActiveBlocksPerMultiprocessor(
        &nb256, (const void*)knet2<256>, 1024, 0);
    if (oe == hipSuccess && nb256 >= 1) {
      hipError_t err = hipLaunchCooperativeKernel(
          reinterpret_cast<void*>(knet2<256>), dim3(256), dim3(1024), args, 0, stream);
      if (err == hipSuccess) return;
    }
  }

  {
    int nb = 0;
    hipError_t oe = hipOccupancyMaxActiveBlocksPerMultiprocessor(
        &nb, (const void*)knet, 256, 0);
    int bpc = (oe == hipSuccess && nb >= 1) ? (nb > 1 ? 1 : nb) : 1;
    void* args[] = { &y_seq, &x0, &h0, &A, &Cm, &W1, &b1, &W_ih, &W_hh,
                     &b_ih, &b_hh, &W2, &b2, &W3, &b3, &out, &ws };
    hipLaunchCooperativeKernel(
        reinterpret_cast<void*>(knet), dim3(256 * bpc), dim3(256), args, 0, stream);
  }
}

// Round 10
// 18404.492 us; speedup vs baseline: 1.9747x; 1.9687x over previous
//
#include <hip/hip_runtime.h>
#include <hip/hip_cooperative_groups.h>

namespace cg = cooperative_groups;

#define T_STEPS 256
// sizes: M=4 N=48 H1=4160 HID=2320 3HID=6960 H2=768 OUT=192 KGIN=52

// ---------------- ws byte-offset layout ----------------
#define O_BAR   0                  // barrier state (memset each launch)
#define O_ZP    256                // 96*4 f32 z-partials
#define O_HF    2048               // 2 x 2320 f32 (h state, parity)
#define HF_STR  9280
#define O_HB    20608              // 2 x 2336 bf16 (h state bf16, parity)
#define HB_STR  4672
#define O_GI    30208              // 6960 f32
#define O_GH    58048              // 6960 f32
// packed weights: pk[job][kt][lane] 16B fragments, per-wave contiguous streams
#define O_PIH   86016              // 435 jobs * 130 kt * 1024B = 57,907,200
#define O_PHH   57993216           // 435 jobs *  73 kt * 1024B = 32,517,120
#define O_W2B   90510336           // 768*2320 bf16 row-major   =  3,563,520
#define NEED_MIN 94073856
#define O_W1P   94073856           // 4160*56 bf16 (padded W1)  =    465,920
#define NEED_FULL 94539776

#define N_W2  1781760

// legacy fp32-path offsets (float units) for fallback kernel
#define WS_L1  0
#define WS_H0  4160
#define WS_H1  6480
#define WS_L2  8800
#define WS_V   9568
#define WS_C   12640

typedef __attribute__((ext_vector_type(8))) short bf16x8;
typedef __attribute__((ext_vector_type(4))) float f32x4;

__device__ __forceinline__ float wred(float v) {
#pragma unroll
  for (int m = 32; m; m >>= 1) v += __shfl_xor(v, m, 64);
  return v;
}
__device__ __forceinline__ float dot4(float4 a, float4 b) {
  return a.x * b.x + a.y * b.y + a.z * b.z + a.w * b.w;
}
__device__ __forceinline__ float blo(unsigned u) {
  unsigned t = u << 16; return __builtin_bit_cast(float, t);
}
__device__ __forceinline__ float bhi(unsigned u) {
  unsigned t = u & 0xFFFF0000u; return __builtin_bit_cast(float, t);
}
__device__ __forceinline__ float dot8bb(uint4 w, uint4 x) {
  float s;
  s  = blo(w.x) * blo(x.x) + bhi(w.x) * bhi(x.x);
  s += blo(w.y) * blo(x.y) + bhi(w.y) * bhi(x.y);
  s += blo(w.z) * blo(x.z) + bhi(w.z) * bhi(x.z);
  s += blo(w.w) * blo(x.w) + bhi(w.w) * bhi(x.w);
  return s;
}
__device__ __forceinline__ unsigned short f2bf(float f) {  // RNE
  unsigned u = __builtin_bit_cast(unsigned, f);
  unsigned r = u + 0x7FFF + ((u >> 16) & 1);
  return (unsigned short)(r >> 16);
}

// ---- scoped accessors: cross-block data via coherence point, no invalidates
__device__ __forceinline__ void st_ag_f32(float* p, float v) {
  __hip_atomic_store(p, v, __ATOMIC_RELAXED, __HIP_MEMORY_SCOPE_AGENT);
}
__device__ __forceinline__ float ld_ag_f32(const float* p) {
  return __hip_atomic_load(p, __ATOMIC_RELAXED, __HIP_MEMORY_SCOPE_AGENT);
}
__device__ __forceinline__ void st_ag_u32(unsigned* p, unsigned v) {
  __hip_atomic_store(p, v, __ATOMIC_RELAXED, __HIP_MEMORY_SCOPE_AGENT);
}
__device__ __forceinline__ unsigned long long ld_ag_u64(const unsigned long long* p) {
  return __hip_atomic_load(p, __ATOMIC_RELAXED, __HIP_MEMORY_SCOPE_AGENT);
}

// ---------- two-level grid barrier (256 blocks = 8 groups x 32) ----------
__device__ __forceinline__ void gbar(unsigned* bar, int bid, unsigned target) {
  __syncthreads();
  if (threadIdx.x == 0) {
    unsigned* grp   = bar + (bid & 7);
    unsigned* lead  = bar + 8;
    unsigned* epoch = bar + 9;
    unsigned old = __hip_atomic_fetch_add(grp, 1u, __ATOMIC_RELEASE, __HIP_MEMORY_SCOPE_AGENT);
    if (old == 31u) {
      __hip_atomic_store(grp, 0u, __ATOMIC_RELAXED, __HIP_MEMORY_SCOPE_AGENT);
      unsigned lo = __hip_atomic_fetch_add(lead, 1u, __ATOMIC_ACQ_REL, __HIP_MEMORY_SCOPE_AGENT);
      if (lo == 7u) {
        __hip_atomic_store(lead, 0u, __ATOMIC_RELAXED, __HIP_MEMORY_SCOPE_AGENT);
        __hip_atomic_store(epoch, target, __ATOMIC_RELEASE, __HIP_MEMORY_SCOPE_AGENT);
      } else {
        while (__hip_atomic_load(epoch, __ATOMIC_RELAXED, __HIP_MEMORY_SCOPE_AGENT) < target)
          __builtin_amdgcn_s_sleep(1);
      }
    } else {
      while (__hip_atomic_load(epoch, __ATOMIC_RELAXED, __HIP_MEMORY_SCOPE_AGENT) < target)
        __builtin_amdgcn_s_sleep(1);
    }
  }
  __syncthreads();
}

// ---------------- pre-pass kernels ----------------
// pack W (row-major f32, njobs*16 rows x K) into pk[job][kt][lane] bf16 fragments:
// lane l of the consuming wave reads row (l&15), cols kt*32+(l>>4)*8 .. +7.
__global__ __launch_bounds__(256) void k_pack(const float* __restrict__ W,
                                              uint4* __restrict__ dst,
                                              int K, int NKT, int n) {
  int idx = blockIdx.x * 256 + threadIdx.x;
  int stride = gridDim.x * 256;
  for (; idx < n; idx += stride) {
    int l = idx & 63;
    int u = idx >> 6;
    int kt = u % NKT;
    int job = u / NKT;
    int g = job / 145, jt = job - g * 145;
    int row = g * 2320 + jt * 16 + (l & 15);
    int col = kt * 32 + ((l >> 4) << 3);
    const float* src = W + (size_t)row * K + col;
    unsigned short o[8];
    if (col + 7 < K) {
#pragma unroll
      for (int i = 0; i < 8; i++) o[i] = f2bf(src[i]);
    } else {
#pragma unroll
      for (int i = 0; i < 8; i++) o[i] = (col + i < K) ? f2bf(src[i]) : (unsigned short)0;
    }
    uint4 v;
    v.x = (unsigned)o[0] | ((unsigned)o[1] << 16);
    v.y = (unsigned)o[2] | ((unsigned)o[3] << 16);
    v.z = (unsigned)o[4] | ((unsigned)o[5] << 16);
    v.w = (unsigned)o[6] | ((unsigned)o[7] << 16);
    dst[idx] = v;
  }
}
__global__ __launch_bounds__(256) void k_cvt(const float4* __restrict__ src,
                                             ushort4* __restrict__ dst, int n4) {
  int i = blockIdx.x * 256 + threadIdx.x, st = gridDim.x * 256;
  for (; i < n4; i += st) {
    float4 v = src[i];
    ushort4 o;
    o.x = f2bf(v.x); o.y = f2bf(v.y); o.z = f2bf(v.z); o.w = f2bf(v.w);
    dst[i] = o;
  }
}
__global__ __launch_bounds__(256) void k_cvtw1(const float* __restrict__ W1,
                                               unsigned short* __restrict__ dst) {
  int i = blockIdx.x * 256 + threadIdx.x;           // over 4160*56
  if (i < 4160 * 56) {
    int r = i / 56, c = i - r * 56;
    dst[i] = (c < 52) ? f2bf(W1[r * 52 + c]) : (unsigned short)0;
  }
}
__global__ __launch_bounds__(256) void k_h0(const float* __restrict__ h0,
                                            unsigned short* __restrict__ hb0,
                                            unsigned short* __restrict__ hb1) {
  int j = blockIdx.x * 256 + threadIdx.x;
  if (j < 2336) {
    hb1[j] = (j < 2320) ? f2bf(h0[j]) : (unsigned short)0;
    if (j >= 2320) hb0[j] = 0;
  }
}

// ================= main 2-sync kernel (256 blocks x 1024 threads) =================
// R7-9 lesson: NO occupancy-API calls in the launch path (they fail under graph
// capture, silently routing the timed run to the fp32 fallback). Direct launch,
// exact R6 structure; only the GEMV weight addressing changed to the packed
// per-wave-contiguous layout (identical bf16 values, identical summation order).
__global__ __launch_bounds__(1024, 4) void knet2(
    const float* __restrict__ y_seq, const float* __restrict__ x0,
    const float* __restrict__ h0, const float* __restrict__ A,
    const float* __restrict__ Cm, const float* __restrict__ W1,
    const float* __restrict__ b1, const float* __restrict__ b_ih,
    const float* __restrict__ b_hh, const float* __restrict__ b2,
    const float* __restrict__ W3, const float* __restrict__ b3,
    float* __restrict__ out, char* __restrict__ wsb, int use_w1p)
{
  const int tid  = threadIdx.x;
  const int lane = tid & 63;
  const int wav  = tid >> 6;
  const int bid  = blockIdx.x;

  unsigned* bar = (unsigned*)(wsb + O_BAR);
  float* zp  = (float*)(wsb + O_ZP);
  float* gi  = (float*)(wsb + O_GI);
  float* gh  = (float*)(wsb + O_GH);
  const unsigned short* bw2 = (const unsigned short*)(wsb + O_W2B);
  const uint4* w1p = (const uint4*)(wsb + O_W1P);

  __shared__ __align__(16) uint4 s_l1u[520];     // l1 bf16
  __shared__ __align__(16) uint4 s_h4u[292];     // h bf16 (MFMA operand)
  __shared__ __align__(16) unsigned short s_h2[2336];  // h_new bf16 (C)
  __shared__ float s_part[4][4][16];
  __shared__ __align__(16) unsigned short s_kgb[64];
  __shared__ __align__(16) float s_kgf[52];
  __shared__ float s_innov[48];
  __shared__ float s_a[192];
  __shared__ float s_l2loc[8];
  __shared__ float s_xpost[4], s_xprior[4], s_dx[4];
  __shared__ float s_sc2, s_sc4;

  unsigned ep = 0;

  for (int t = 0; t <= T_STEPS; ++t) {
    // ======== prologue: x_post(t) from z-partials(t-1) [all blocks] ========
    if (t == 0) {
      if (tid < 4) s_xpost[tid] = x0[tid];
    } else {
      if (tid < 4) {
        float z = 0.f;
        for (int p = 0; p < 96; ++p) z += ld_ag_f32(&zp[p * 4 + tid]);
        float cb = 0.f;
        for (int j = 0; j < 48; ++j) cb += s_innov[j] * b3[tid * 48 + j];
        float xn = s_xprior[tid] + (z + cb) * 1e-4f;
        s_xpost[tid] = xn;
        if (bid == 0) out[tid * T_STEPS + (t - 1)] = xn;
      }
    }
    __syncthreads();
    if (t == T_STEPS) return;

    // ======== small math: x_prior, innov, kg_in ========
    if (tid < 4) {
      float xpr = 0.f;
#pragma unroll
      for (int j = 0; j < 4; j++) xpr += A[tid * 4 + j] * s_xpost[j];
      s_xprior[tid] = xpr;
    }
    __syncthreads();
    if (tid < 48) {
      float yp = Cm[tid * 5 + 4];
#pragma unroll
      for (int j = 0; j < 4; j++) yp += Cm[tid * 5 + j] * s_xprior[j];
      s_innov[tid] = y_seq[tid * T_STEPS + t] - yp;
    }
    if (tid >= 64 && tid < 68) {
      int i = tid - 64;
      s_dx[i] = s_xpost[i] - s_xprior[i];
    }
    __syncthreads();
    if (tid == 0) {
      float s2 = 0.f;
      for (int r = 0; r < 48; r++) s2 += s_innov[r] * s_innov[r];
      s_sc2 = 1.0f / fmaxf(sqrtf(s2), 1e-12f);
      float s4 = 0.f;
      for (int i = 0; i < 4; i++) s4 += s_dx[i] * s_dx[i];
      s_sc4 = 1.0f / fmaxf(sqrtf(s4), 1e-12f);
    }
    __syncthreads();
    if (tid < 64) {
      float v = (tid < 48) ? s_innov[tid] * s_sc2
              : (tid < 52) ? s_dx[tid - 48] * s_sc4 : 0.f;
      s_kgb[tid] = f2bf(v);
      if (tid < 52) s_kgf[tid] = v;
    }
    // stage h(t-1) bf16 into LDS via agent loads
    {
      const unsigned long long* hbg =
          (const unsigned long long*)(wsb + O_HB + ((t + 1) & 1) * HB_STR);
      unsigned long long* dst = (unsigned long long*)s_h4u;
      if (tid < 584) dst[tid] = ld_ag_u64(hbg + tid);
    }
    __syncthreads();

    // ======== l1 = relu(W1 @ kg + b1), redundant per block ========
    if (use_w1p) {
      const uint4* kg4 = (const uint4*)s_kgb;
      for (int r = tid; r < 4160; r += 1024) {
        const uint4* wr = w1p + (size_t)r * 7;
        float acc = b1[r];
#pragma unroll
        for (int c = 0; c < 7; c++) acc += dot8bb(wr[c], kg4[c]);
        ((unsigned short*)s_l1u)[r] = f2bf(fmaxf(acc, 0.f));
      }
    } else {
      const float4* kg4 = (const float4*)s_kgf;
      for (int r = tid; r < 4160; r += 1024) {
        const float4* wr = (const float4*)(W1 + (size_t)r * 52);
        float acc = b1[r];
#pragma unroll
        for (int c = 0; c < 13; c++) acc += dot4(wr[c], kg4[c]);
        ((unsigned short*)s_l1u)[r] = f2bf(fmaxf(acc, 0.f));
      }
    }
    __syncthreads();

    // ======== GRU GEMV via MFMA, packed contiguous streams, 8-deep prefetch ====
    {
      const int q  = wav >> 2;        // job slot 0..3
      const int kw = wav & 3;         // k-split
      const int job = bid + 256 * q;
      if (job < 870) {
        const int side = (job < 435) ? 0 : 1;
        const int xoff = lane >> 4;
        const uint4* xs;
        const uint4* wp;
        int kbeg, kend;
        if (side == 0) {
          xs = s_l1u;
          kbeg = kw * 33; kend = kbeg + 33; if (kend > 130) kend = 130;
          wp = (const uint4*)(wsb + O_PIH) + ((size_t)job * 130 + kbeg) * 64 + lane;
        } else {
          xs = s_h4u;
          kbeg = kw * 19; kend = kbeg + 19; if (kend > 73) kend = 73;
          wp = (const uint4*)(wsb + O_PHH) + ((size_t)(job - 435) * 73 + kbeg) * 64 + lane;
        }
        f32x4 acc = {0.f, 0.f, 0.f, 0.f};
        uint4 b0  = wp[0 * 64];
        uint4 b1r = wp[1 * 64];
        uint4 b2r = wp[2 * 64];
        uint4 b3r = wp[3 * 64];
        uint4 b4  = wp[4 * 64];
        uint4 b5  = wp[5 * 64];
        uint4 b6  = wp[6 * 64];
        uint4 b7  = wp[7 * 64];
        int kt = kbeg;
#define GSTEP(P, B) { acc = __builtin_amdgcn_mfma_f32_16x16x32_bf16( \
            __builtin_bit_cast(bf16x8, B), \
            __builtin_bit_cast(bf16x8, xs[(kt + P) * 4 + xoff]), acc, 0, 0, 0); \
            B = wp[(size_t)(kt - kbeg + 8 + P) * 64]; }
        while (kt + 8 <= kend) {
          GSTEP(0, b0) GSTEP(1, b1r) GSTEP(2, b2r) GSTEP(3, b3r)
          GSTEP(4, b4) GSTEP(5, b5)  GSTEP(6, b6)  GSTEP(7, b7)
          kt += 8;
        }
#undef GSTEP
#define TSTEP(P, B) if (kt + P < kend) acc = __builtin_amdgcn_mfma_f32_16x16x32_bf16( \
            __builtin_bit_cast(bf16x8, B), \
            __builtin_bit_cast(bf16x8, xs[(kt + P) * 4 + xoff]), acc, 0, 0, 0);
        TSTEP(0, b0) TSTEP(1, b1r) TSTEP(2, b2r) TSTEP(3, b3r)
        TSTEP(4, b4) TSTEP(5, b5)  TSTEP(6, b6)  TSTEP(7, b7)
#undef TSTEP
        if ((lane & 15) == 0) {
          int rb = (lane >> 4) * 4;
#pragma unroll
          for (int i = 0; i < 4; i++) s_part[q][kw][rb + i] = acc[i];
        }
      }
    }
    __syncthreads();
    if (tid < 64) {
      int q = tid >> 4, r = tid & 15;
      int job = bid + 256 * q;
      if (job < 870) {
        float s = s_part[q][0][r] + s_part[q][1][r] + s_part[q][2][r] + s_part[q][3][r];
        if (job < 435) st_ag_f32(&gi[job * 16 + r], s);
        else st_ag_f32(&gh[(job - 435) * 16 + r], s);
      }
    }
    ++ep; gbar(bar, bid, ep);   // -------- SYNC 1: gi/gh ready --------

    // ======== C: gates (96 blocks, redundant), l2, z-partials ========
    if (bid < 96) {
      float* hf_out = (float*)(wsb + O_HF + (t & 1) * HF_STR);
      unsigned* hb_out32 = (unsigned*)(wsb + O_HB + (t & 1) * HB_STR);
      const float* hf_old = (const float*)(wsb + O_HF + ((t + 1) & 1) * HF_STR);
      for (int j = tid; j < 2320; j += 1024) {
        float ir = ld_ag_f32(&gi[j]) + b_ih[j];
        float iz = ld_ag_f32(&gi[2320 + j]) + b_ih[2320 + j];
        float ig = ld_ag_f32(&gi[4640 + j]) + b_ih[4640 + j];
        float hr = ld_ag_f32(&gh[j]) + b_hh[j];
        float hz = ld_ag_f32(&gh[2320 + j]) + b_hh[2320 + j];
        float hg = ld_ag_f32(&gh[4640 + j]) + b_hh[4640 + j];
        float rr = 1.f / (1.f + expf(-(ir + hr)));
        float zz = 1.f / (1.f + expf(-(iz + hz)));
        float gg = tanhf(ig + rr * hg);
        float hold = (t == 0) ? h0[j] : ld_ag_f32(&hf_old[j]);
        float hn = (1.f - zz) * gg + zz * hold;
        s_h2[j] = f2bf(hn);
        if (bid == 0) st_ag_f32(&hf_out[j], hn);
      }
      if (tid < 16) s_h2[2320 + tid] = 0;   // keep K-pad zero
      __syncthreads();
      // publish h_new bf16 (bid 0 only), packed u32 agent stores
      if (bid == 0 && tid < 1168) {
        unsigned v = (unsigned)s_h2[2 * tid] | ((unsigned)s_h2[2 * tid + 1] << 16);
        st_ag_u32(hb_out32 + tid, v);
      }
      // l2 rows (8 per block), bf16 VALU dot from LDS
      if (wav < 8) {
        const int row = bid * 8 + wav;
        const uint4* wr = (const uint4*)(bw2 + (size_t)row * 2320);
        const uint4* hx = (const uint4*)s_h2;
        float acc = 0.f;
        for (int k = lane; k < 290; k += 64) acc += dot8bb(wr[k], hx[k]);
        acc = wred(acc);
        if (lane == 0) s_l2loc[wav] = fmaxf(acc + b2[row], 0.f);
      }
      __syncthreads();
      // z-partials
      if (tid < 192) {
        const float* w3r = W3 + (size_t)tid * 768 + bid * 8;
        float a = 0.f;
#pragma unroll
        for (int r = 0; r < 8; r++) a += w3r[r] * s_l2loc[r];
        s_a[tid] = a * s_innov[tid % 48];
      }
      __syncthreads();
      if (tid < 4) {
        float zv = 0.f;
        for (int j = 0; j < 48; j++) zv += s_a[tid * 48 + j];
        st_ag_f32(&zp[bid * 4 + tid], zv);
      }
    }
    ++ep; gbar(bar, bid, ep);   // -------- SYNC 2: h/l2/z ready --------
  }
}

// ================= cooperative fp32 kernel (proven fallback) =================
__global__ __launch_bounds__(256, 2) void knet(
    const float* __restrict__ y_seq, const float* __restrict__ x0,
    const float* __restrict__ h0, const float* __restrict__ A,
    const float* __restrict__ Cm, const float* __restrict__ W1,
    const float* __restrict__ b1, const float* __restrict__ W_ih,
    const float* __restrict__ W_hh, const float* __restrict__ b_ih,
    const float* __restrict__ b_hh, const float* __restrict__ W2,
    const float* __restrict__ b2, const float* __restrict__ W3,
    const float* __restrict__ b3, float* __restrict__ out,
    float* __restrict__ ws)
{
  cg::grid_group grid = cg::this_grid();
  const int tid = threadIdx.x, lane = tid & 63, wav = tid >> 6, bid = blockIdx.x;
  const int gt = bid * 256 + tid, wave_g = bid * 4 + wav, NW = gridDim.x * 4;

  __shared__ __align__(16) float4 s_buf4[1040];
  __shared__ __align__(16) float4 s_h4[580];
  __shared__ __align__(16) float s_kgin[52];
  __shared__ float s_innov[48];
  __shared__ float s_xpost[4], s_xprior[4], s_dx[4];
  __shared__ float s_sc2, s_sc4;

  for (int t = 0; t <= T_STEPS; ++t) {
    if (t == 0) {
      if (tid < 4) s_xpost[tid] = x0[tid];
    } else {
      const float4* vv  = (const float4*)(ws + WS_V + wav * 768);
      const float4* l2v = (const float4*)(ws + WS_L2);
      float acc = 0.f;
      for (int k = lane; k < 192; k += 64) acc += dot4(vv[k], l2v[k]);
      acc = wred(acc);
      if (lane == 0)
        s_xpost[wav] = s_xprior[wav] + (acc + ws[WS_C + wav]) * 1e-4f;
    }
    __syncthreads();
    if (bid == 0 && t > 0 && tid < 4) out[tid * T_STEPS + (t - 1)] = s_xpost[tid];
    if (t == T_STEPS) return;

    if (tid < 4) {
      float xp = 0.f;
#pragma unroll
      for (int j = 0; j < 4; j++) xp += A[tid * 4 + j] * s_xpost[j];
      s_xprior[tid] = xp;
    }
    __syncthreads();
    if (tid < 48) {
      float yp = Cm[tid * 5 + 4];
#pragma unroll
      for (int j = 0; j < 4; j++) yp += Cm[tid * 5 + j] * s_xprior[j];
      s_innov[tid] = y_seq[tid * T_STEPS + t] - yp;
    }
    if (tid >= 64 && tid < 68) {
      int i = tid - 64;
      s_dx[i] = s_xpost[i] - s_xprior[i];
    }
    __syncthreads();
    if (tid == 0) {
      float s2 = 0.f;
      for (int r = 0; r < 48; r++) s2 += s_innov[r] * s_innov[r];
      s_sc2 = 1.0f / fmaxf(sqrtf(s2), 1e-12f);
      float s4 = 0.f;
      for (int i = 0; i < 4; i++) s4 += s_dx[i] * s_dx[i];
      s_sc4 = 1.0f / fmaxf(sqrtf(s4), 1e-12f);
    }
    __syncthreads();
    if (tid < 48) s_kgin[tid] = s_innov[tid] * s_sc2;
    else if (tid < 52) s_kgin[tid] = s_dx[tid - 48] * s_sc4;
    __syncthreads();

    if (gt < 4160) {
      const float4* wr  = (const float4*)(W1 + (size_t)gt * 52);
      const float4* kg4 = (const float4*)s_kgin;
      float acc = b1[gt];
#pragma unroll
      for (int k = 0; k < 13; k++) acc += dot4(wr[k], kg4[k]);
      ws[WS_L1 + gt] = fmaxf(acc, 0.f);
    }
    grid.sync();

    {
      const float* h_old = (t == 0) ? h0 : (ws + (((t & 1) == 0) ? WS_H0 : WS_H1));
      float* h_new = ws + (((t & 1) == 0) ? WS_H1 : WS_H0);
      const float4* l1g = (const float4*)(ws + WS_L1);
      for (int i = tid; i < 1040; i += 256) s_buf4[i] = l1g[i];
      const float4* hog = (const float4*)h_old;
      for (int i = tid; i < 580; i += 256) s_h4[i] = hog[i];
      __syncthreads();
      const float* s_h = (const float*)s_h4;

      for (int j = wave_g; j < 2320; j += NW) {
        const float4* r0 = (const float4*)(W_ih + (size_t)j * 4160);
        const float4* r1 = (const float4*)(W_ih + (size_t)(j + 2320) * 4160);
        const float4* r2 = (const float4*)(W_ih + (size_t)(j + 4640) * 4160);
        float a0 = 0.f, a1 = 0.f, a2 = 0.f;
#pragma unroll 4
        for (int k = lane; k < 1040; k += 64) {
          float4 x = s_buf4[k];
          a0 += dot4(r0[k], x); a1 += dot4(r1[k], x); a2 += dot4(r2[k], x);
        }
        const float4* q0 = (const float4*)(W_hh + (size_t)j * 2320);
        const float4* q1 = (const float4*)(W_hh + (size_t)(j + 2320) * 2320);
        const float4* q2 = (const float4*)(W_hh + (size_t)(j + 4640) * 2320);
        float c0 = 0.f, c1 = 0.f, c2 = 0.f;
#pragma unroll 4
        for (int k = lane; k < 580; k += 64) {
          float4 x = s_h4[k];
          c0 += dot4(q0[k], x); c1 += dot4(q1[k], x); c2 += dot4(q2[k], x);
        }
        a0 = wred(a0); a1 = wred(a1); a2 = wred(a2);
        c0 = wred(c0); c1 = wred(c1); c2 = wred(c2);
        if (lane == 0) {
          float ir = a0 + b_ih[j], iz = a1 + b_ih[j + 2320], ig = a2 + b_ih[j + 4640];
          float hr = c0 + b_hh[j], hz = c1 + b_hh[j + 2320], hg = c2 + b_hh[j + 4640];
          float rr = 1.f / (1.f + expf(-(ir + hr)));
          float zz = 1.f / (1.f + expf(-(iz + hz)));
          float gg = tanhf(ig + rr * hg);
          h_new[j] = (1.f - zz) * gg + zz * s_h[j];
        }
      }
    }
    grid.sync();

    {
      const float* h_new = ws + (((t & 1) == 0) ? WS_H1 : WS_H0);
      const float4* hv = (const float4*)h_new;
      for (int i = tid; i < 580; i += 256) s_buf4[i] = hv[i];
      __syncthreads();

      if (gt < 3072) {
        int i = gt / 768, cc = gt - i * 768;
        const float* wcol = W3 + (size_t)(i * 48) * 768 + cc;
        float acc = 0.f;
#pragma unroll 8
        for (int j = 0; j < 48; j++) acc += s_innov[j] * wcol[(size_t)j * 768];
        ws[WS_V + gt] = acc;
      } else if (gt < 3076) {
        int i = gt - 3072;
        float acc = 0.f;
        for (int j = 0; j < 48; j++) acc += s_innov[j] * b3[i * 48 + j];
        ws[WS_C + i] = acc;
      }

      for (int task = wave_g; task < 768; task += NW) {
        const float4* row = (const float4*)(W2 + (size_t)task * 2320);
        float acc = 0.f;
#pragma unroll 4
        for (int k = lane; k < 580; k += 64) acc += dot4(row[k], s_buf4[k]);
        acc = wred(acc);
        if (lane == 0) ws[WS_L2 + task] = fmaxf(acc + b2[task], 0.f);
      }
    }
    grid.sync();
  }
}

extern "C" void kernel_launch(void* const* d_in, const int* in_sizes, int n_in,
                              void* d_out, int out_size, void* d_ws, size_t ws_size,
                              hipStream_t stream) {
  const float* y_seq = (const float*)d_in[0];
  const float* x0    = (const float*)d_in[1];
  const float* h0    = (const float*)d_in[2];
  const float* A     = (const float*)d_in[3];
  const float* Cm    = (const float*)d_in[4];
  const float* W1    = (const float*)d_in[5];
  const float* b1    = (const float*)d_in[6];
  const float* W_ih  = (const float*)d_in[7];
  const float* W_hh  = (const float*)d_in[8];
  const float* b_ih  = (const float*)d_in[9];
  const float* b_hh  = (const float*)d_in[10];
  const float* W2    = (const float*)d_in[11];
  const float* b2    = (const float*)d_in[12];
  const float* W3    = (const float*)d_in[13];
  const float* b3    = (const float*)d_in[14];
  float* out = (float*)d_out;
  float* ws  = (float*)d_ws;
  char* wsb  = (char*)d_ws;

  if (ws_size >= NEED_MIN) {
    int use_w1p = (ws_size >= NEED_FULL) ? 1 : 0;
    hipMemsetAsync(wsb + O_BAR, 0, 256, stream);
    // pack W_ih: 435 jobs x 130 kt x 64 lanes
    k_pack<<<8192, 256, 0, stream>>>(W_ih, (uint4*)(wsb + O_PIH),
                                     4160, 130, 435 * 130 * 64);
    // pack W_hh: 435 jobs x 73 kt x 64 lanes (tail kt zero-padded past col 2320)
    k_pack<<<8192, 256, 0, stream>>>(W_hh, (uint4*)(wsb + O_PHH),
                                     2320, 73, 435 * 73 * 64);
    k_cvt<<<512, 256, 0, stream>>>((const float4*)W2,
                                   (ushort4*)(wsb + O_W2B), N_W2 / 4);
    if (use_w1p)
      k_cvtw1<<<(4160 * 56 + 255) / 256, 256, 0, stream>>>(
          W1, (unsigned short*)(wsb + O_W1P));
    k_h0<<<10, 256, 0, stream>>>(h0, (unsigned short*)(wsb + O_HB),
                                 (unsigned short*)(wsb + O_HB + HB_STR));

    void* args[] = { &y_seq, &x0, &h0, &A, &Cm, &W1, &b1, &b_ih, &b_hh,
                     &b2, &W3, &b3, &out, &wsb, &use_w1p };
    // DIRECT launch (no occupancy queries — they fail under graph capture)
    hipError_t err = hipLaunchCooperativeKernel(
        reinterpret_cast<void*>(knet2), dim3(256), dim3(1024), args, 0, stream);
    if (err == hipSuccess) return;
  }

  {
    void* args[] = { &y_seq, &x0, &h0, &A, &Cm, &W1, &b1, &W_ih, &W_hh,
                     &b_ih, &b_hh, &W2, &b2, &W3, &b3, &out, &ws };
    hipLaunchCooperativeKernel(
        reinterpret_cast<void*>(knet), dim3(256), dim3(256), args, 0, stream);
  }
}

// Round 11
// 11468.667 us; speedup vs baseline: 3.1689x; 1.6048x over previous
//
#include <hip/hip_runtime.h>
#include <hip/hip_cooperative_groups.h>

namespace cg = cooperative_groups;

#define T_STEPS 256
// sizes: M=4 N=48 H1=4160 HID=2320 3HID=6960 H2=768 OUT=192 KGIN=52

// ---------------- ws byte-offset layout ----------------
#define O_SLOT  0                  // 256 u32 arrival slots (memset w/ epoch)
#define O_EPOCH 1024               // 1 u32 epoch
#define O_ZP    2048               // 96*4 f32 z-partials (room to 6144)
#define O_HF    6144               // 2 x 2320 f32 (h state, parity)
#define HF_STR  9280
#define O_HB    24704              // 2 x 2336 bf16 (h state bf16, parity)
#define HB_STR  4672
#define O_GI    34048              // 6960 f32
#define O_GH    61888              // 6960 f32
// packed weights: pk[job][kt][lane] 16B fragments, per-wave contiguous streams
#define O_PIH   90112              // 435 jobs * 130 kt * 1024B = 57,907,200
#define O_PHH   57997312           // 435 jobs *  73 kt * 1024B = 32,517,120
#define O_W2B   90514432           // 768*2320 bf16 row-major   =  3,563,520
#define NEED_MIN 94077952
#define O_W1P   94077952           // 4160*56 bf16 (padded W1)  =    465,920
#define NEED_FULL 94543872

#define N_W2  1781760

// legacy fp32-path offsets (float units) for fallback kernel
#define WS_L1  0
#define WS_H0  4160
#define WS_H1  6480
#define WS_L2  8800
#define WS_V   9568
#define WS_C   12640

typedef __attribute__((ext_vector_type(8))) short bf16x8;
typedef __attribute__((ext_vector_type(4))) float f32x4;

__device__ __forceinline__ float wred(float v) {
#pragma unroll
  for (int m = 32; m; m >>= 1) v += __shfl_xor(v, m, 64);
  return v;
}
__device__ __forceinline__ float dot4(float4 a, float4 b) {
  return a.x * b.x + a.y * b.y + a.z * b.z + a.w * b.w;
}
__device__ __forceinline__ float blo(unsigned u) {
  unsigned t = u << 16; return __builtin_bit_cast(float, t);
}
__device__ __forceinline__ float bhi(unsigned u) {
  unsigned t = u & 0xFFFF0000u; return __builtin_bit_cast(float, t);
}
__device__ __forceinline__ float dot8bb(uint4 w, uint4 x) {
  float s;
  s  = blo(w.x) * blo(x.x) + bhi(w.x) * bhi(x.x);
  s += blo(w.y) * blo(x.y) + bhi(w.y) * bhi(x.y);
  s += blo(w.z) * blo(x.z) + bhi(w.z) * bhi(x.z);
  s += blo(w.w) * blo(x.w) + bhi(w.w) * bhi(x.w);
  return s;
}
__device__ __forceinline__ unsigned short f2bf(float f) {  // RNE
  unsigned u = __builtin_bit_cast(unsigned, f);
  unsigned r = u + 0x7FFF + ((u >> 16) & 1);
  return (unsigned short)(r >> 16);
}

// ---- scoped accessors: cross-block data via coherence point, no invalidates
__device__ __forceinline__ void st_ag_f32(float* p, float v) {
  __hip_atomic_store(p, v, __ATOMIC_RELAXED, __HIP_MEMORY_SCOPE_AGENT);
}
__device__ __forceinline__ float ld_ag_f32(const float* p) {
  return __hip_atomic_load(p, __ATOMIC_RELAXED, __HIP_MEMORY_SCOPE_AGENT);
}
__device__ __forceinline__ void st_ag_u32(unsigned* p, unsigned v) {
  __hip_atomic_store(p, v, __ATOMIC_RELAXED, __HIP_MEMORY_SCOPE_AGENT);
}
__device__ __forceinline__ unsigned long long ld_ag_u64(const unsigned long long* p) {
  return __hip_atomic_load(p, __ATOMIC_RELAXED, __HIP_MEMORY_SCOPE_AGENT);
}

// ---------- slot barrier: parallel release-store arrivals (no contended RMW),
// ---------- block 0 detects via 255 concurrent agent loads, epoch release ----------
__device__ __forceinline__ void gbar(char* wsb, int bid, unsigned target, int* s_ok) {
  unsigned* slot  = (unsigned*)(wsb + O_SLOT);
  unsigned* epoch = (unsigned*)(wsb + O_EPOCH);
  const int tid = threadIdx.x;
  __syncthreads();   // all block stores drained before arrival is published
  if (bid == 0) {
    for (;;) {
      if (tid == 0) *s_ok = 1;
      __syncthreads();
      if (tid >= 1 && tid < 256) {
        if (__hip_atomic_load(&slot[tid], __ATOMIC_RELAXED, __HIP_MEMORY_SCOPE_AGENT) < target)
          *s_ok = 0;               // benign race: all writers write 0
      }
      __syncthreads();
      if (*s_ok) break;
      __builtin_amdgcn_s_sleep(2);
    }
    if (tid == 0)
      __hip_atomic_store(epoch, target, __ATOMIC_RELEASE, __HIP_MEMORY_SCOPE_AGENT);
    __syncthreads();
  } else {
    if (tid == 0) {
      __hip_atomic_store(&slot[bid], target, __ATOMIC_RELEASE, __HIP_MEMORY_SCOPE_AGENT);
      while (__hip_atomic_load(epoch, __ATOMIC_RELAXED, __HIP_MEMORY_SCOPE_AGENT) < target)
        __builtin_amdgcn_s_sleep(1);
    }
    __syncthreads();
  }
}

// ---------------- pre-pass kernels ----------------
// pack W (row-major f32, njobs*16 rows x K) into pk[job][kt][lane] bf16 fragments:
// lane l of the consuming wave reads row (l&15), cols kt*32+(l>>4)*8 .. +7.
__global__ __launch_bounds__(256) void k_pack(const float* __restrict__ W,
                                              uint4* __restrict__ dst,
                                              int K, int NKT, int n) {
  int idx = blockIdx.x * 256 + threadIdx.x;
  int stride = gridDim.x * 256;
  for (; idx < n; idx += stride) {
    int l = idx & 63;
    int u = idx >> 6;
    int kt = u % NKT;
    int job = u / NKT;
    int g = job / 145, jt = job - g * 145;
    int row = g * 2320 + jt * 16 + (l & 15);
    int col = kt * 32 + ((l >> 4) << 3);
    const float* src = W + (size_t)row * K + col;
    unsigned short o[8];
    if (col + 7 < K) {
#pragma unroll
      for (int i = 0; i < 8; i++) o[i] = f2bf(src[i]);
    } else {
#pragma unroll
      for (int i = 0; i < 8; i++) o[i] = (col + i < K) ? f2bf(src[i]) : (unsigned short)0;
    }
    uint4 v;
    v.x = (unsigned)o[0] | ((unsigned)o[1] << 16);
    v.y = (unsigned)o[2] | ((unsigned)o[3] << 16);
    v.z = (unsigned)o[4] | ((unsigned)o[5] << 16);
    v.w = (unsigned)o[6] | ((unsigned)o[7] << 16);
    dst[idx] = v;
  }
}
__global__ __launch_bounds__(256) void k_cvt(const float4* __restrict__ src,
                                             ushort4* __restrict__ dst, int n4) {
  int i = blockIdx.x * 256 + threadIdx.x, st = gridDim.x * 256;
  for (; i < n4; i += st) {
    float4 v = src[i];
    ushort4 o;
    o.x = f2bf(v.x); o.y = f2bf(v.y); o.z = f2bf(v.z); o.w = f2bf(v.w);
    dst[i] = o;
  }
}
__global__ __launch_bounds__(256) void k_cvtw1(const float* __restrict__ W1,
                                               unsigned short* __restrict__ dst) {
  int i = blockIdx.x * 256 + threadIdx.x;           // over 4160*56
  if (i < 4160 * 56) {
    int r = i / 56, c = i - r * 56;
    dst[i] = (c < 52) ? f2bf(W1[r * 52 + c]) : (unsigned short)0;
  }
}
__global__ __launch_bounds__(256) void k_h0(const float* __restrict__ h0,
                                            unsigned short* __restrict__ hb0,
                                            unsigned short* __restrict__ hb1) {
  int j = blockIdx.x * 256 + threadIdx.x;
  if (j < 2336) {
    hb1[j] = (j < 2320) ? f2bf(h0[j]) : (unsigned short)0;
    if (j >= 2320) hb0[j] = 0;
  }
}

// ================= main 2-sync kernel (256 blocks x 1024 threads) =================
// R10 isolation: GEMV/job-map/C-phase identical; ONLY sync mechanics changed:
// (1) slot barrier (parallel arrivals, no serialized same-line RMW chain),
// (2) zp gather parallelized (384 threads x 1 agent load -> LDS; summation
//     order p=0..95 unchanged -> numerics bit-identical to R10, absmax 0.125).
__global__ __launch_bounds__(1024, 4) void knet2(
    const float* __restrict__ y_seq, const float* __restrict__ x0,
    const float* __restrict__ h0, const float* __restrict__ A,
    const float* __restrict__ Cm, const float* __restrict__ W1,
    const float* __restrict__ b1, const float* __restrict__ b_ih,
    const float* __restrict__ b_hh, const float* __restrict__ b2,
    const float* __restrict__ W3, const float* __restrict__ b3,
    float* __restrict__ out, char* __restrict__ wsb, int use_w1p)
{
  const int tid  = threadIdx.x;
  const int lane = tid & 63;
  const int wav  = tid >> 6;
  const int bid  = blockIdx.x;

  float* zp  = (float*)(wsb + O_ZP);
  float* gi  = (float*)(wsb + O_GI);
  float* gh  = (float*)(wsb + O_GH);
  const unsigned short* bw2 = (const unsigned short*)(wsb + O_W2B);
  const uint4* w1p = (const uint4*)(wsb + O_W1P);

  __shared__ __align__(16) uint4 s_l1u[520];     // l1 bf16
  __shared__ __align__(16) uint4 s_h4u[292];     // h bf16 (MFMA operand)
  __shared__ __align__(16) unsigned short s_h2[2336];  // h_new bf16 (C)
  __shared__ float s_part[4][4][16];
  __shared__ __align__(16) unsigned short s_kgb[64];
  __shared__ __align__(16) float s_kgf[52];
  __shared__ float s_innov[48];
  __shared__ float s_a[192];
  __shared__ float s_zred[384];
  __shared__ float s_l2loc[8];
  __shared__ float s_xpost[4], s_xprior[4], s_dx[4];
  __shared__ float s_sc2, s_sc4;
  __shared__ int s_ok;

  unsigned ep = 0;

  for (int t = 0; t <= T_STEPS; ++t) {
    // ======== prologue: x_post(t) from z-partials(t-1) [all blocks] ========
    if (t == 0) {
      if (tid < 4) s_xpost[tid] = x0[tid];
    } else {
      if (tid < 384) s_zred[tid] = ld_ag_f32(&zp[tid]);   // parallel gather
      __syncthreads();
      if (tid < 4) {
        float z = 0.f;
#pragma unroll 8
        for (int p = 0; p < 96; ++p) z += s_zred[p * 4 + tid];  // same order as R10
        float cb = 0.f;
        for (int j = 0; j < 48; ++j) cb += s_innov[j] * b3[tid * 48 + j];
        float xn = s_xprior[tid] + (z + cb) * 1e-4f;
        s_xpost[tid] = xn;
        if (bid == 0) out[tid * T_STEPS + (t - 1)] = xn;
      }
    }
    __syncthreads();
    if (t == T_STEPS) return;

    // ======== small math: x_prior, innov, kg_in ========
    if (tid < 4) {
      float xpr = 0.f;
#pragma unroll
      for (int j = 0; j < 4; j++) xpr += A[tid * 4 + j] * s_xpost[j];
      s_xprior[tid] = xpr;
    }
    __syncthreads();
    if (tid < 48) {
      float yp = Cm[tid * 5 + 4];
#pragma unroll
      for (int j = 0; j < 4; j++) yp += Cm[tid * 5 + j] * s_xprior[j];
      s_innov[tid] = y_seq[tid * T_STEPS + t] - yp;
    }
    if (tid >= 64 && tid < 68) {
      int i = tid - 64;
      s_dx[i] = s_xpost[i] - s_xprior[i];
    }
    __syncthreads();
    if (tid == 0) {
      float s2 = 0.f;
      for (int r = 0; r < 48; r++) s2 += s_innov[r] * s_innov[r];
      s_sc2 = 1.0f / fmaxf(sqrtf(s2), 1e-12f);
      float s4 = 0.f;
      for (int i = 0; i < 4; i++) s4 += s_dx[i] * s_dx[i];
      s_sc4 = 1.0f / fmaxf(sqrtf(s4), 1e-12f);
    }
    __syncthreads();
    if (tid < 64) {
      float v = (tid < 48) ? s_innov[tid] * s_sc2
              : (tid < 52) ? s_dx[tid - 48] * s_sc4 : 0.f;
      s_kgb[tid] = f2bf(v);
      if (tid < 52) s_kgf[tid] = v;
    }
    // stage h(t-1) bf16 into LDS via agent loads
    {
      const unsigned long long* hbg =
          (const unsigned long long*)(wsb + O_HB + ((t + 1) & 1) * HB_STR);
      unsigned long long* dst = (unsigned long long*)s_h4u;
      if (tid < 584) dst[tid] = ld_ag_u64(hbg + tid);
    }
    __syncthreads();

    // ======== l1 = relu(W1 @ kg + b1), redundant per block ========
    if (use_w1p) {
      const uint4* kg4 = (const uint4*)s_kgb;
      for (int r = tid; r < 4160; r += 1024) {
        const uint4* wr = w1p + (size_t)r * 7;
        float acc = b1[r];
#pragma unroll
        for (int c = 0; c < 7; c++) acc += dot8bb(wr[c], kg4[c]);
        ((unsigned short*)s_l1u)[r] = f2bf(fmaxf(acc, 0.f));
      }
    } else {
      const float4* kg4 = (const float4*)s_kgf;
      for (int r = tid; r < 4160; r += 1024) {
        const float4* wr = (const float4*)(W1 + (size_t)r * 52);
        float acc = b1[r];
#pragma unroll
        for (int c = 0; c < 13; c++) acc += dot4(wr[c], kg4[c]);
        ((unsigned short*)s_l1u)[r] = f2bf(fmaxf(acc, 0.f));
      }
    }
    __syncthreads();

    // ======== GRU GEMV via MFMA, packed contiguous streams, 8-deep prefetch ====
    {
      const int q  = wav >> 2;        // job slot 0..3
      const int kw = wav & 3;         // k-split
      const int job = bid + 256 * q;
      if (job < 870) {
        const int side = (job < 435) ? 0 : 1;
        const int xoff = lane >> 4;
        const uint4* xs;
        const uint4* wp;
        int kbeg, kend;
        if (side == 0) {
          xs = s_l1u;
          kbeg = kw * 33; kend = kbeg + 33; if (kend > 130) kend = 130;
          wp = (const uint4*)(wsb + O_PIH) + ((size_t)job * 130 + kbeg) * 64 + lane;
        } else {
          xs = s_h4u;
          kbeg = kw * 19; kend = kbeg + 19; if (kend > 73) kend = 73;
          wp = (const uint4*)(wsb + O_PHH) + ((size_t)(job - 435) * 73 + kbeg) * 64 + lane;
        }
        f32x4 acc = {0.f, 0.f, 0.f, 0.f};
        uint4 b0  = wp[0 * 64];
        uint4 b1r = wp[1 * 64];
        uint4 b2r = wp[2 * 64];
        uint4 b3r = wp[3 * 64];
        uint4 b4  = wp[4 * 64];
        uint4 b5  = wp[5 * 64];
        uint4 b6  = wp[6 * 64];
        uint4 b7  = wp[7 * 64];
        int kt = kbeg;
#define GSTEP(P, B) { acc = __builtin_amdgcn_mfma_f32_16x16x32_bf16( \
            __builtin_bit_cast(bf16x8, B), \
            __builtin_bit_cast(bf16x8, xs[(kt + P) * 4 + xoff]), acc, 0, 0, 0); \
            B = wp[(size_t)(kt - kbeg + 8 + P) * 64]; }
        while (kt + 8 <= kend) {
          GSTEP(0, b0) GSTEP(1, b1r) GSTEP(2, b2r) GSTEP(3, b3r)
          GSTEP(4, b4) GSTEP(5, b5)  GSTEP(6, b6)  GSTEP(7, b7)
          kt += 8;
        }
#undef GSTEP
#define TSTEP(P, B) if (kt + P < kend) acc = __builtin_amdgcn_mfma_f32_16x16x32_bf16( \
            __builtin_bit_cast(bf16x8, B), \
            __builtin_bit_cast(bf16x8, xs[(kt + P) * 4 + xoff]), acc, 0, 0, 0);
        TSTEP(0, b0) TSTEP(1, b1r) TSTEP(2, b2r) TSTEP(3, b3r)
        TSTEP(4, b4) TSTEP(5, b5)  TSTEP(6, b6)  TSTEP(7, b7)
#undef TSTEP
        if ((lane & 15) == 0) {
          int rb = (lane >> 4) * 4;
#pragma unroll
          for (int i = 0; i < 4; i++) s_part[q][kw][rb + i] = acc[i];
        }
      }
    }
    __syncthreads();
    if (tid < 64) {
      int q = tid >> 4, r = tid & 15;
      int job = bid + 256 * q;
      if (job < 870) {
        float s = s_part[q][0][r] + s_part[q][1][r] + s_part[q][2][r] + s_part[q][3][r];
        if (job < 435) st_ag_f32(&gi[job * 16 + r], s);
        else st_ag_f32(&gh[(job - 435) * 16 + r], s);
      }
    }
    ++ep; gbar(wsb, bid, ep, &s_ok);   // -------- SYNC 1: gi/gh ready --------

    // ======== C: gates (96 blocks, redundant), l2, z-partials ========
    if (bid < 96) {
      float* hf_out = (float*)(wsb + O_HF + (t & 1) * HF_STR);
      unsigned* hb_out32 = (unsigned*)(wsb + O_HB + (t & 1) * HB_STR);
      const float* hf_old = (const float*)(wsb + O_HF + ((t + 1) & 1) * HF_STR);
      for (int j = tid; j < 2320; j += 1024) {
        float ir = ld_ag_f32(&gi[j]) + b_ih[j];
        float iz = ld_ag_f32(&gi[2320 + j]) + b_ih[2320 + j];
        float ig = ld_ag_f32(&gi[4640 + j]) + b_ih[4640 + j];
        float hr = ld_ag_f32(&gh[j]) + b_hh[j];
        float hz = ld_ag_f32(&gh[2320 + j]) + b_hh[2320 + j];
        float hg = ld_ag_f32(&gh[4640 + j]) + b_hh[4640 + j];
        float rr = 1.f / (1.f + expf(-(ir + hr)));
        float zz = 1.f / (1.f + expf(-(iz + hz)));
        float gg = tanhf(ig + rr * hg);
        float hold = (t == 0) ? h0[j] : ld_ag_f32(&hf_old[j]);
        float hn = (1.f - zz) * gg + zz * hold;
        s_h2[j] = f2bf(hn);
        if (bid == 0) st_ag_f32(&hf_out[j], hn);
      }
      if (tid < 16) s_h2[2320 + tid] = 0;   // keep K-pad zero
      __syncthreads();
      // publish h_new bf16 (bid 0 only), packed u32 agent stores
      if (bid == 0 && tid < 1168) {
        unsigned v = (unsigned)s_h2[2 * tid] | ((unsigned)s_h2[2 * tid + 1] << 16);
        st_ag_u32(hb_out32 + tid, v);
      }
      // l2 rows (8 per block), bf16 VALU dot from LDS
      if (wav < 8) {
        const int row = bid * 8 + wav;
        const uint4* wr = (const uint4*)(bw2 + (size_t)row * 2320);
        const uint4* hx = (const uint4*)s_h2;
        float acc = 0.f;
        for (int k = lane; k < 290; k += 64) acc += dot8bb(wr[k], hx[k]);
        acc = wred(acc);
        if (lane == 0) s_l2loc[wav] = fmaxf(acc + b2[row], 0.f);
      }
      __syncthreads();
      // z-partials
      if (tid < 192) {
        const float* w3r = W3 + (size_t)tid * 768 + bid * 8;
        float a = 0.f;
#pragma unroll
        for (int r = 0; r < 8; r++) a += w3r[r] * s_l2loc[r];
        s_a[tid] = a * s_innov[tid % 48];
      }
      __syncthreads();
      if (tid < 4) {
        float zv = 0.f;
        for (int j = 0; j < 48; j++) zv += s_a[tid * 48 + j];
        st_ag_f32(&zp[bid * 4 + tid], zv);
      }
    }
    ++ep; gbar(wsb, bid, ep, &s_ok);   // -------- SYNC 2: h/l2/z ready --------
  }
}

// ================= cooperative fp32 kernel (proven fallback) =================
__global__ __launch_bounds__(256, 2) void knet(
    const float* __restrict__ y_seq, const float* __restrict__ x0,
    const float* __restrict__ h0, const float* __restrict__ A,
    const float* __restrict__ Cm, const float* __restrict__ W1,
    const float* __restrict__ b1, const float* __restrict__ W_ih,
    const float* __restrict__ W_hh, const float* __restrict__ b_ih,
    const float* __restrict__ b_hh, const float* __restrict__ W2,
    const float* __restrict__ b2, const float* __restrict__ W3,
    const float* __restrict__ b3, float* __restrict__ out,
    float* __restrict__ ws)
{
  cg::grid_group grid = cg::this_grid();
  const int tid = threadIdx.x, lane = tid & 63, wav = tid >> 6, bid = blockIdx.x;
  const int gt = bid * 256 + tid, wave_g = bid * 4 + wav, NW = gridDim.x * 4;

  __shared__ __align__(16) float4 s_buf4[1040];
  __shared__ __align__(16) float4 s_h4[580];
  __shared__ __align__(16) float s_kgin[52];
  __shared__ float s_innov[48];
  __shared__ float s_xpost[4], s_xprior[4], s_dx[4];
  __shared__ float s_sc2, s_sc4;

  for (int t = 0; t <= T_STEPS; ++t) {
    if (t == 0) {
      if (tid < 4) s_xpost[tid] = x0[tid];
    } else {
      const float4* vv  = (const float4*)(ws + WS_V + wav * 768);
      const float4* l2v = (const float4*)(ws + WS_L2);
      float acc = 0.f;
      for (int k = lane; k < 192; k += 64) acc += dot4(vv[k], l2v[k]);
      acc = wred(acc);
      if (lane == 0)
        s_xpost[wav] = s_xprior[wav] + (acc + ws[WS_C + wav]) * 1e-4f;
    }
    __syncthreads();
    if (bid == 0 && t > 0 && tid < 4) out[tid * T_STEPS + (t - 1)] = s_xpost[tid];
    if (t == T_STEPS) return;

    if (tid < 4) {
      float xp = 0.f;
#pragma unroll
      for (int j = 0; j < 4; j++) xp += A[tid * 4 + j] * s_xpost[j];
      s_xprior[tid] = xp;
    }
    __syncthreads();
    if (tid < 48) {
      float yp = Cm[tid * 5 + 4];
#pragma unroll
      for (int j = 0; j < 4; j++) yp += Cm[tid * 5 + j] * s_xprior[j];
      s_innov[tid] = y_seq[tid * T_STEPS + t] - yp;
    }
    if (tid >= 64 && tid < 68) {
      int i = tid - 64;
      s_dx[i] = s_xpost[i] - s_xprior[i];
    }
    __syncthreads();
    if (tid == 0) {
      float s2 = 0.f;
      for (int r = 0; r < 48; r++) s2 += s_innov[r] * s_innov[r];
      s_sc2 = 1.0f / fmaxf(sqrtf(s2), 1e-12f);
      float s4 = 0.f;
      for (int i = 0; i < 4; i++) s4 += s_dx[i] * s_dx[i];
      s_sc4 = 1.0f / fmaxf(sqrtf(s4), 1e-12f);
    }
    __syncthreads();
    if (tid < 48) s_kgin[tid] = s_innov[tid] * s_sc2;
    else if (tid < 52) s_kgin[tid] = s_dx[tid - 48] * s_sc4;
    __syncthreads();

    if (gt < 4160) {
      const float4* wr  = (const float4*)(W1 + (size_t)gt * 52);
      const float4* kg4 = (const float4*)s_kgin;
      float acc = b1[gt];
#pragma unroll
      for (int k = 0; k < 13; k++) acc += dot4(wr[k], kg4[k]);
      ws[WS_L1 + gt] = fmaxf(acc, 0.f);
    }
    grid.sync();

    {
      const float* h_old = (t == 0) ? h0 : (ws + (((t & 1) == 0) ? WS_H0 : WS_H1));
      float* h_new = ws + (((t & 1) == 0) ? WS_H1 : WS_H0);
      const float4* l1g = (const float4*)(ws + WS_L1);
      for (int i = tid; i < 1040; i += 256) s_buf4[i] = l1g[i];
      const float4* hog = (const float4*)h_old;
      for (int i = tid; i < 580; i += 256) s_h4[i] = hog[i];
      __syncthreads();
      const float* s_h = (const float*)s_h4;

      for (int j = wave_g; j < 2320; j += NW) {
        const float4* r0 = (const float4*)(W_ih + (size_t)j * 4160);
        const float4* r1 = (const float4*)(W_ih + (size_t)(j + 2320) * 4160);
        const float4* r2 = (const float4*)(W_ih + (size_t)(j + 4640) * 4160);
        float a0 = 0.f, a1 = 0.f, a2 = 0.f;
#pragma unroll 4
        for (int k = lane; k < 1040; k += 64) {
          float4 x = s_buf4[k];
          a0 += dot4(r0[k], x); a1 += dot4(r1[k], x); a2 += dot4(r2[k], x);
        }
        const float4* q0 = (const float4*)(W_hh + (size_t)j * 2320);
        const float4* q1 = (const float4*)(W_hh + (size_t)(j + 2320) * 2320);
        const float4* q2 = (const float4*)(W_hh + (size_t)(j + 4640) * 2320);
        float c0 = 0.f, c1 = 0.f, c2 = 0.f;
#pragma unroll 4
        for (int k = lane; k < 580; k += 64) {
          float4 x = s_h4[k];
          c0 += dot4(q0[k], x); c1 += dot4(q1[k], x); c2 += dot4(q2[k], x);
        }
        a0 = wred(a0); a1 = wred(a1); a2 = wred(a2);
        c0 = wred(c0); c1 = wred(c1); c2 = wred(c2);
        if (lane == 0) {
          float ir = a0 + b_ih[j], iz = a1 + b_ih[j + 2320], ig = a2 + b_ih[j + 4640];
          float hr = c0 + b_hh[j], hz = c1 + b_hh[j + 2320], hg = c2 + b_hh[j + 4640];
          float rr = 1.f / (1.f + expf(-(ir + hr)));
          float zz = 1.f / (1.f + expf(-(iz + hz)));
          float gg = tanhf(ig + rr * hg);
          h_new[j] = (1.f - zz) * gg + zz * s_h[j];
        }
      }
    }
    grid.sync();

    {
      const float* h_new = ws + (((t & 1) == 0) ? WS_H1 : WS_H0);
      const float4* hv = (const float4*)h_new;
      for (int i = tid; i < 580; i += 256) s_buf4[i] = hv[i];
      __syncthreads();

      if (gt < 3072) {
        int i = gt / 768, cc = gt - i * 768;
        const float* wcol = W3 + (size_t)(i * 48) * 768 + cc;
        float acc = 0.f;
#pragma unroll 8
        for (int j = 0; j < 48; j++) acc += s_innov[j] * wcol[(size_t)j * 768];
        ws[WS_V + gt] = acc;
      } else if (gt < 3076) {
        int i = gt - 3072;
        float acc = 0.f;
        for (int j = 0; j < 48; j++) acc += s_innov[j] * b3[i * 48 + j];
        ws[WS_C + i] = acc;
      }

      for (int task = wave_g; task < 768; task += NW) {
        const float4* row = (const float4*)(W2 + (size_t)task * 2320);
        float acc = 0.f;
#pragma unroll 4
        for (int k = lane; k < 580; k += 64) acc += dot4(row[k], s_buf4[k]);
        acc = wred(acc);
        if (lane == 0) ws[WS_L2 + task] = fmaxf(acc + b2[task], 0.f);
      }
    }
    grid.sync();
  }
}

extern "C" void kernel_launch(void* const* d_in, const int* in_sizes, int n_in,
                              void* d_out, int out_size, void* d_ws, size_t ws_size,
                              hipStream_t stream) {
  const float* y_seq = (const float*)d_in[0];
  const float* x0    = (const float*)d_in[1];
  const float* h0    = (const float*)d_in[2];
  const float* A     = (const float*)d_in[3];
  const float* Cm    = (const float*)d_in[4];
  const float* W1    = (const float*)d_in[5];
  const float* b1    = (const float*)d_in[6];
  const float* W_ih  = (const float*)d_in[7];
  const float* W_hh  = (const float*)d_in[8];
  const float* b_ih  = (const float*)d_in[9];
  const float* b_hh  = (const float*)d_in[10];
  const float* W2    = (const float*)d_in[11];
  const float* b2    = (const float*)d_in[12];
  const float* W3    = (const float*)d_in[13];
  const float* b3    = (const float*)d_in[14];
  float* out = (float*)d_out;
  float* ws  = (float*)d_ws;
  char* wsb  = (char*)d_ws;

  if (ws_size >= NEED_MIN) {
    int use_w1p = (ws_size >= NEED_FULL) ? 1 : 0;
    hipMemsetAsync(wsb + O_SLOT, 0, 2048, stream);   // slots + epoch
    // pack W_ih: 435 jobs x 130 kt x 64 lanes
    k_pack<<<8192, 256, 0, stream>>>(W_ih, (uint4*)(wsb + O_PIH),
                                     4160, 130, 435 * 130 * 64);
    // pack W_hh: 435 jobs x 73 kt x 64 lanes (tail kt zero-padded past col 2320)
    k_pack<<<8192, 256, 0, stream>>>(W_hh, (uint4*)(wsb + O_PHH),
                                     2320, 73, 435 * 73 * 64);
    k_cvt<<<512, 256, 0, stream>>>((const float4*)W2,
                                   (ushort4*)(wsb + O_W2B), N_W2 / 4);
    if (use_w1p)
      k_cvtw1<<<(4160 * 56 + 255) / 256, 256, 0, stream>>>(
          W1, (unsigned short*)(wsb + O_W1P));
    k_h0<<<10, 256, 0, stream>>>(h0, (unsigned short*)(wsb + O_HB),
                                 (unsigned short*)(wsb + O_HB + HB_STR));

    void* args[] = { &y_seq, &x0, &h0, &A, &Cm, &W1, &b1, &b_ih, &b_hh,
                     &b2, &W3, &b3, &out, &wsb, &use_w1p };
    // DIRECT launch (no occupancy queries — they fail under graph capture)
    hipError_t err = hipLaunchCooperativeKernel(
        reinterpret_cast<void*>(knet2), dim3(256), dim3(1024), args, 0, stream);
    if (err == hipSuccess) return;
  }

  {
    void* args[] = { &y_seq, &x0, &h0, &A, &Cm, &W1, &b1, &W_ih, &W_hh,
                     &b_ih, &b_hh, &W2, &b2, &W3, &b3, &out, &ws };
    hipLaunchCooperativeKernel(
        reinterpret_cast<void*>(knet), dim3(256), dim3(256), args, 0, stream);
  }
}

// Round 12
// 10719.136 us; speedup vs baseline: 3.3904x; 1.0699x over previous
//
#include <hip/hip_runtime.h>
#include <hip/hip_cooperative_groups.h>

namespace cg = cooperative_groups;

#define T_STEPS 256
// sizes: M=4 N=48 H1=4160 HID=2320 3HID=6960 H2=768 OUT=192 KGIN=52

// ---------------- ws byte-offset layout ----------------
#define O_SLOT  0                  // 256 u32 arrival slots
#define O_EPOCH 1024               // 1 u32 epoch
#define O_ZP    2048               // 96*4 f32 z-partials
#define O_HF    6144               // 2 x 2320 f32 (h state, parity)
#define HF_STR  9280               // ends 24704
#define O_HB    24704              // 2 x 2336 bf16 (h bf16, parity)
#define HB_STR  4672               // ends 34048
#define O_GI4   34048              // 2320*4 f32 interleaved (r,z,g,pad) -> 37120
#define O_GH4   71168              // 2320*4 f32 -> ends 108288
// packed weights: pk[job][kt][lane] 16B fragments, per-wave contiguous streams
#define O_PIH   108544             // 435 jobs * 130 kt * 1024B = 57,907,200
#define O_PHH   58015744           // 435 jobs *  73 kt * 1024B = 32,517,120
#define O_W2B   90532864           // 768*2320 bf16 row-major   =  3,563,520
#define NEED_MIN 94096384
#define O_W1P   94096384           // 4160*56 bf16 (padded W1)  =    465,920
#define NEED_FULL 94562304

#define N_W2  1781760
#define PIN_U4 (130 * 64)          // 8320 uint4 = 133,120 B pinned per block
#define DYN_LDS 133120

// legacy fp32-path offsets (float units) for fallback kernel
#define WS_L1  0
#define WS_H0  4160
#define WS_H1  6480
#define WS_L2  8800
#define WS_V   9568
#define WS_C   12640

typedef __attribute__((ext_vector_type(8))) short bf16x8;
typedef __attribute__((ext_vector_type(4))) float f32x4;
typedef unsigned long long u64t;

__device__ __forceinline__ float wred(float v) {
#pragma unroll
  for (int m = 32; m; m >>= 1) v += __shfl_xor(v, m, 64);
  return v;
}
__device__ __forceinline__ float dot4(float4 a, float4 b) {
  return a.x * b.x + a.y * b.y + a.z * b.z + a.w * b.w;
}
__device__ __forceinline__ float blo(unsigned u) {
  unsigned t = u << 16; return __builtin_bit_cast(float, t);
}
__device__ __forceinline__ float bhi(unsigned u) {
  unsigned t = u & 0xFFFF0000u; return __builtin_bit_cast(float, t);
}
__device__ __forceinline__ float dot8bb(uint4 w, uint4 x) {
  float s;
  s  = blo(w.x) * blo(x.x) + bhi(w.x) * bhi(x.x);
  s += blo(w.y) * blo(x.y) + bhi(w.y) * bhi(x.y);
  s += blo(w.z) * blo(x.z) + bhi(w.z) * bhi(x.z);
  s += blo(w.w) * blo(x.w) + bhi(w.w) * bhi(x.w);
  return s;
}
__device__ __forceinline__ unsigned short f2bf(float f) {  // RNE
  unsigned u = __builtin_bit_cast(unsigned, f);
  unsigned r = u + 0x7FFF + ((u >> 16) & 1);
  return (unsigned short)(r >> 16);
}
__device__ __forceinline__ float u2f_lo(u64t v) {
  unsigned u = (unsigned)(v & 0xFFFFFFFFull);
  return __builtin_bit_cast(float, u);
}
__device__ __forceinline__ float u2f_hi(u64t v) {
  unsigned u = (unsigned)(v >> 32);
  return __builtin_bit_cast(float, u);
}

// ---- scoped accessors: cross-block data via coherence point, no invalidates
__device__ __forceinline__ void st_ag_f32(float* p, float v) {
  __hip_atomic_store(p, v, __ATOMIC_RELAXED, __HIP_MEMORY_SCOPE_AGENT);
}
__device__ __forceinline__ float ld_ag_f32(const float* p) {
  return __hip_atomic_load(p, __ATOMIC_RELAXED, __HIP_MEMORY_SCOPE_AGENT);
}
__device__ __forceinline__ void st_ag_u32(unsigned* p, unsigned v) {
  __hip_atomic_store(p, v, __ATOMIC_RELAXED, __HIP_MEMORY_SCOPE_AGENT);
}
__device__ __forceinline__ u64t ld_ag_u64(const u64t* p) {
  return __hip_atomic_load(p, __ATOMIC_RELAXED, __HIP_MEMORY_SCOPE_AGENT);
}

// ---------- slot barrier (R11-proven): parallel release-store arrivals ----------
__device__ __forceinline__ void gbar(char* wsb, int bid, unsigned target, int* s_ok) {
  unsigned* slot  = (unsigned*)(wsb + O_SLOT);
  unsigned* epoch = (unsigned*)(wsb + O_EPOCH);
  const int tid = threadIdx.x;
  __syncthreads();
  if (bid == 0) {
    for (;;) {
      if (tid == 0) *s_ok = 1;
      __syncthreads();
      if (tid >= 1 && tid < 256) {
        if (__hip_atomic_load(&slot[tid], __ATOMIC_RELAXED, __HIP_MEMORY_SCOPE_AGENT) < target)
          *s_ok = 0;
      }
      __syncthreads();
      if (*s_ok) break;
      __builtin_amdgcn_s_sleep(2);
    }
    if (tid == 0)
      __hip_atomic_store(epoch, target, __ATOMIC_RELEASE, __HIP_MEMORY_SCOPE_AGENT);
    __syncthreads();
  } else {
    if (tid == 0) {
      __hip_atomic_store(&slot[bid], target, __ATOMIC_RELEASE, __HIP_MEMORY_SCOPE_AGENT);
      while (__hip_atomic_load(epoch, __ATOMIC_RELAXED, __HIP_MEMORY_SCOPE_AGENT) < target)
        __builtin_amdgcn_s_sleep(1);
    }
    __syncthreads();
  }
}

// ---------------- pre-pass kernels ----------------
__global__ __launch_bounds__(256) void k_pack(const float* __restrict__ W,
                                              uint4* __restrict__ dst,
                                              int K, int NKT, int n) {
  int idx = blockIdx.x * 256 + threadIdx.x;
  int stride = gridDim.x * 256;
  for (; idx < n; idx += stride) {
    int l = idx & 63;
    int u = idx >> 6;
    int kt = u % NKT;
    int job = u / NKT;
    int g = job / 145, jt = job - g * 145;
    int row = g * 2320 + jt * 16 + (l & 15);
    int col = kt * 32 + ((l >> 4) << 3);
    const float* src = W + (size_t)row * K + col;
    unsigned short o[8];
    if (col + 7 < K) {
#pragma unroll
      for (int i = 0; i < 8; i++) o[i] = f2bf(src[i]);
    } else {
#pragma unroll
      for (int i = 0; i < 8; i++) o[i] = (col + i < K) ? f2bf(src[i]) : (unsigned short)0;
    }
    uint4 v;
    v.x = (unsigned)o[0] | ((unsigned)o[1] << 16);
    v.y = (unsigned)o[2] | ((unsigned)o[3] << 16);
    v.z = (unsigned)o[4] | ((unsigned)o[5] << 16);
    v.w = (unsigned)o[6] | ((unsigned)o[7] << 16);
    dst[idx] = v;
  }
}
__global__ __launch_bounds__(256) void k_cvt(const float4* __restrict__ src,
                                             ushort4* __restrict__ dst, int n4) {
  int i = blockIdx.x * 256 + threadIdx.x, st = gridDim.x * 256;
  for (; i < n4; i += st) {
    float4 v = src[i];
    ushort4 o;
    o.x = f2bf(v.x); o.y = f2bf(v.y); o.z = f2bf(v.z); o.w = f2bf(v.w);
    dst[i] = o;
  }
}
__global__ __launch_bounds__(256) void k_cvtw1(const float* __restrict__ W1,
                                               unsigned short* __restrict__ dst) {
  int i = blockIdx.x * 256 + threadIdx.x;           // over 4160*56
  if (i < 4160 * 56) {
    int r = i / 56, c = i - r * 56;
    dst[i] = (c < 52) ? f2bf(W1[r * 52 + c]) : (unsigned short)0;
  }
}
__global__ __launch_bounds__(256) void k_h0(const float* __restrict__ h0,
                                            unsigned short* __restrict__ hb0,
                                            unsigned short* __restrict__ hb1) {
  int j = blockIdx.x * 256 + threadIdx.x;
  if (j < 2336) {
    hb1[j] = (j < 2320) ? f2bf(h0[j]) : (unsigned short)0;
    if (j >= 2320) hb0[j] = 0;
  }
}

// ================= main 2-sync kernel (256 blocks x 1024 threads) =================
// R12: (1) pin each block's q0 ih-job (130 KB packed bf16) in dynamic LDS once at
// t=0 — removes 33 MB/step from the beyond-L2 stream with ZERO numeric change;
// (2) gi/gh stored interleaved [j*4+g] -> C phase reads 4 u64 agent loads/row
// instead of 6 scalar. Same values, same summation order -> absmax 0.125 exact.
__global__ __launch_bounds__(1024, 4) void knet2(
    const float* __restrict__ y_seq, const float* __restrict__ x0,
    const float* __restrict__ h0, const float* __restrict__ A,
    const float* __restrict__ Cm, const float* __restrict__ W1,
    const float* __restrict__ b1, const float* __restrict__ b_ih,
    const float* __restrict__ b_hh, const float* __restrict__ b2,
    const float* __restrict__ W3, const float* __restrict__ b3,
    float* __restrict__ out, char* __restrict__ wsb, int use_w1p)
{
  const int tid  = threadIdx.x;
  const int lane = tid & 63;
  const int wav  = tid >> 6;
  const int bid  = blockIdx.x;

  float* zp  = (float*)(wsb + O_ZP);
  float* gi4 = (float*)(wsb + O_GI4);
  float* gh4 = (float*)(wsb + O_GH4);
  const unsigned short* bw2 = (const unsigned short*)(wsb + O_W2B);
  const uint4* w1p = (const uint4*)(wsb + O_W1P);

  extern __shared__ __align__(16) char dynsmem[];
  uint4* pin = (uint4*)dynsmem;                  // 130 kt x 64 lanes, q0 job

  __shared__ __align__(16) uint4 s_l1u[520];     // l1 bf16
  __shared__ __align__(16) uint4 s_h4u[292];     // h bf16 (MFMA operand)
  __shared__ __align__(16) unsigned short s_h2[2336];  // h_new bf16 (C)
  __shared__ float s_part[4][4][16];
  __shared__ __align__(16) unsigned short s_kgb[64];
  __shared__ __align__(16) float s_kgf[52];
  __shared__ float s_innov[48];
  __shared__ float s_a[192];
  __shared__ float s_zred[384];
  __shared__ float s_l2loc[8];
  __shared__ float s_xpost[4], s_xprior[4], s_dx[4];
  __shared__ float s_sc2, s_sc4;
  __shared__ int s_ok;

  // ---- one-time: pin this block's q0 (ih) job weights into LDS ----
  {
    const uint4* src = (const uint4*)(wsb + O_PIH) + (size_t)bid * PIN_U4;
    for (int i = tid; i < PIN_U4; i += 1024) pin[i] = src[i];
  }

  unsigned ep = 0;

  for (int t = 0; t <= T_STEPS; ++t) {
    // ======== prologue: x_post(t) from z-partials(t-1) [all blocks] ========
    if (t == 0) {
      if (tid < 4) s_xpost[tid] = x0[tid];
    } else {
      if (tid < 384) s_zred[tid] = ld_ag_f32(&zp[tid]);   // parallel gather
      __syncthreads();
      if (tid < 4) {
        float z = 0.f;
#pragma unroll 8
        for (int p = 0; p < 96; ++p) z += s_zred[p * 4 + tid];
        float cb = 0.f;
        for (int j = 0; j < 48; ++j) cb += s_innov[j] * b3[tid * 48 + j];
        float xn = s_xprior[tid] + (z + cb) * 1e-4f;
        s_xpost[tid] = xn;
        if (bid == 0) out[tid * T_STEPS + (t - 1)] = xn;
      }
    }
    __syncthreads();
    if (t == T_STEPS) return;

    // ======== small math: x_prior, innov, kg_in ========
    if (tid < 4) {
      float xpr = 0.f;
#pragma unroll
      for (int j = 0; j < 4; j++) xpr += A[tid * 4 + j] * s_xpost[j];
      s_xprior[tid] = xpr;
    }
    __syncthreads();
    if (tid < 48) {
      float yp = Cm[tid * 5 + 4];
#pragma unroll
      for (int j = 0; j < 4; j++) yp += Cm[tid * 5 + j] * s_xprior[j];
      s_innov[tid] = y_seq[tid * T_STEPS + t] - yp;
    }
    if (tid >= 64 && tid < 68) {
      int i = tid - 64;
      s_dx[i] = s_xpost[i] - s_xprior[i];
    }
    __syncthreads();
    if (tid == 0) {
      float s2 = 0.f;
      for (int r = 0; r < 48; r++) s2 += s_innov[r] * s_innov[r];
      s_sc2 = 1.0f / fmaxf(sqrtf(s2), 1e-12f);
      float s4 = 0.f;
      for (int i = 0; i < 4; i++) s4 += s_dx[i] * s_dx[i];
      s_sc4 = 1.0f / fmaxf(sqrtf(s4), 1e-12f);
    }
    __syncthreads();
    if (tid < 64) {
      float v = (tid < 48) ? s_innov[tid] * s_sc2
              : (tid < 52) ? s_dx[tid - 48] * s_sc4 : 0.f;
      s_kgb[tid] = f2bf(v);
      if (tid < 52) s_kgf[tid] = v;
    }
    // stage h(t-1) bf16 into LDS via agent loads
    {
      const u64t* hbg = (const u64t*)(wsb + O_HB + ((t + 1) & 1) * HB_STR);
      u64t* dst = (u64t*)s_h4u;
      if (tid < 584) dst[tid] = ld_ag_u64(hbg + tid);
    }
    __syncthreads();

    // ======== l1 = relu(W1 @ kg + b1), redundant per block ========
    if (use_w1p) {
      const uint4* kg4 = (const uint4*)s_kgb;
      for (int r = tid; r < 4160; r += 1024) {
        const uint4* wr = w1p + (size_t)r * 7;
        float acc = b1[r];
#pragma unroll
        for (int c = 0; c < 7; c++) acc += dot8bb(wr[c], kg4[c]);
        ((unsigned short*)s_l1u)[r] = f2bf(fmaxf(acc, 0.f));
      }
    } else {
      const float4* kg4 = (const float4*)s_kgf;
      for (int r = tid; r < 4160; r += 1024) {
        const float4* wr = (const float4*)(W1 + (size_t)r * 52);
        float acc = b1[r];
#pragma unroll
        for (int c = 0; c < 13; c++) acc += dot4(wr[c], kg4[c]);
        ((unsigned short*)s_l1u)[r] = f2bf(fmaxf(acc, 0.f));
      }
    }
    __syncthreads();

    // ======== GRU GEMV via MFMA: q0 from pinned LDS, q1-3 global 8-deep ====
    {
      const int q  = wav >> 2;        // job slot 0..3
      const int kw = wav & 3;         // k-split
      const int job = bid + 256 * q;
      if (job < 870) {
        const int xoff = lane >> 4;
        f32x4 acc = {0.f, 0.f, 0.f, 0.f};
        if (q == 0) {
          // ---- pinned LDS path (ih job 'bid', all 130 kt resident) ----
          int kbeg = kw * 33, kend = kbeg + 33; if (kend > 130) kend = 130;
          const uint4* xs = s_l1u;
          for (int kt = kbeg; kt < kend; ++kt)
            acc = __builtin_amdgcn_mfma_f32_16x16x32_bf16(
                __builtin_bit_cast(bf16x8, pin[kt * 64 + lane]),
                __builtin_bit_cast(bf16x8, xs[kt * 4 + xoff]), acc, 0, 0, 0);
        } else {
          const int side = (job < 435) ? 0 : 1;
          const uint4* xs;
          const uint4* wp;
          int kbeg, kend;
          if (side == 0) {
            xs = s_l1u;
            kbeg = kw * 33; kend = kbeg + 33; if (kend > 130) kend = 130;
            wp = (const uint4*)(wsb + O_PIH) + ((size_t)job * 130 + kbeg) * 64 + lane;
          } else {
            xs = s_h4u;
            kbeg = kw * 19; kend = kbeg + 19; if (kend > 73) kend = 73;
            wp = (const uint4*)(wsb + O_PHH) + ((size_t)(job - 435) * 73 + kbeg) * 64 + lane;
          }
          uint4 b0  = wp[0 * 64];
          uint4 b1r = wp[1 * 64];
          uint4 b2r = wp[2 * 64];
          uint4 b3r = wp[3 * 64];
          uint4 b4  = wp[4 * 64];
          uint4 b5  = wp[5 * 64];
          uint4 b6  = wp[6 * 64];
          uint4 b7  = wp[7 * 64];
          int kt = kbeg;
#define GSTEP(P, B) { acc = __builtin_amdgcn_mfma_f32_16x16x32_bf16( \
              __builtin_bit_cast(bf16x8, B), \
              __builtin_bit_cast(bf16x8, xs[(kt + P) * 4 + xoff]), acc, 0, 0, 0); \
              B = wp[(size_t)(kt - kbeg + 8 + P) * 64]; }
          while (kt + 8 <= kend) {
            GSTEP(0, b0) GSTEP(1, b1r) GSTEP(2, b2r) GSTEP(3, b3r)
            GSTEP(4, b4) GSTEP(5, b5)  GSTEP(6, b6)  GSTEP(7, b7)
            kt += 8;
          }
#undef GSTEP
#define TSTEP(P, B) if (kt + P < kend) acc = __builtin_amdgcn_mfma_f32_16x16x32_bf16( \
              __builtin_bit_cast(bf16x8, B), \
              __builtin_bit_cast(bf16x8, xs[(kt + P) * 4 + xoff]), acc, 0, 0, 0);
          TSTEP(0, b0) TSTEP(1, b1r) TSTEP(2, b2r) TSTEP(3, b3r)
          TSTEP(4, b4) TSTEP(5, b5)  TSTEP(6, b6)  TSTEP(7, b7)
#undef TSTEP
        }
        if ((lane & 15) == 0) {
          int rb = (lane >> 4) * 4;
#pragma unroll
          for (int i = 0; i < 4; i++) s_part[q][kw][rb + i] = acc[i];
        }
      }
    }
    __syncthreads();
    if (tid < 64) {
      int q = tid >> 4, r = tid & 15;
      int job = bid + 256 * q;
      if (job < 870) {
        float s = s_part[q][0][r] + s_part[q][1][r] + s_part[q][2][r] + s_part[q][3][r];
        if (job < 435) {
          int g = job / 145, jt = job - g * 145;
          st_ag_f32(&gi4[(size_t)(jt * 16 + r) * 4 + g], s);
        } else {
          int j2 = job - 435;
          int g = j2 / 145, jt = j2 - g * 145;
          st_ag_f32(&gh4[(size_t)(jt * 16 + r) * 4 + g], s);
        }
      }
    }
    ++ep; gbar(wsb, bid, ep, &s_ok);   // -------- SYNC 1: gi/gh ready --------

    // ======== C: gates (96 blocks, redundant), l2, z-partials ========
    if (bid < 96) {
      float* hf_out = (float*)(wsb + O_HF + (t & 1) * HF_STR);
      unsigned* hb_out32 = (unsigned*)(wsb + O_HB + (t & 1) * HB_STR);
      const float* hf_old = (const float*)(wsb + O_HF + ((t + 1) & 1) * HF_STR);
      const u64t* gi2 = (const u64t*)gi4;
      const u64t* gh2 = (const u64t*)gh4;
      for (int j = tid; j < 2320; j += 1024) {
        u64t ia = ld_ag_u64(&gi2[(size_t)j * 2]);
        u64t ib = ld_ag_u64(&gi2[(size_t)j * 2 + 1]);
        u64t ha = ld_ag_u64(&gh2[(size_t)j * 2]);
        u64t hb = ld_ag_u64(&gh2[(size_t)j * 2 + 1]);
        float ir = u2f_lo(ia) + b_ih[j];
        float iz = u2f_hi(ia) + b_ih[2320 + j];
        float ig = u2f_lo(ib) + b_ih[4640 + j];
        float hr = u2f_lo(ha) + b_hh[j];
        float hz = u2f_hi(ha) + b_hh[2320 + j];
        float hg = u2f_lo(hb) + b_hh[4640 + j];
        float rr = 1.f / (1.f + expf(-(ir + hr)));
        float zz = 1.f / (1.f + expf(-(iz + hz)));
        float gg = tanhf(ig + rr * hg);
        float hold = (t == 0) ? h0[j] : ld_ag_f32(&hf_old[j]);
        float hn = (1.f - zz) * gg + zz * hold;
        s_h2[j] = f2bf(hn);
        if (bid == 0) st_ag_f32(&hf_out[j], hn);
      }
      if (tid < 16) s_h2[2320 + tid] = 0;   // keep K-pad zero
      __syncthreads();
      // publish h_new bf16 (bid 0 only), packed u32 agent stores
      if (bid == 0 && tid < 1168) {
        unsigned v = (unsigned)s_h2[2 * tid] | ((unsigned)s_h2[2 * tid + 1] << 16);
        st_ag_u32(hb_out32 + tid, v);
      }
      // l2 rows (8 per block), bf16 VALU dot from LDS
      if (wav < 8) {
        const int row = bid * 8 + wav;
        const uint4* wr = (const uint4*)(bw2 + (size_t)row * 2320);
        const uint4* hx = (const uint4*)s_h2;
        float acc = 0.f;
        for (int k = lane; k < 290; k += 64) acc += dot8bb(wr[k], hx[k]);
        acc = wred(acc);
        if (lane == 0) s_l2loc[wav] = fmaxf(acc + b2[row], 0.f);
      }
      __syncthreads();
      // z-partials
      if (tid < 192) {
        const float* w3r = W3 + (size_t)tid * 768 + bid * 8;
        float a = 0.f;
#pragma unroll
        for (int r = 0; r < 8; r++) a += w3r[r] * s_l2loc[r];
        s_a[tid] = a * s_innov[tid % 48];
      }
      __syncthreads();
      if (tid < 4) {
        float zv = 0.f;
        for (int j = 0; j < 48; j++) zv += s_a[tid * 48 + j];
        st_ag_f32(&zp[bid * 4 + tid], zv);
      }
    }
    ++ep; gbar(wsb, bid, ep, &s_ok);   // -------- SYNC 2: h/l2/z ready --------
  }
}

// ================= cooperative fp32 kernel (proven fallback) =================
__global__ __launch_bounds__(256, 2) void knet(
    const float* __restrict__ y_seq, const float* __restrict__ x0,
    const float* __restrict__ h0, const float* __restrict__ A,
    const float* __restrict__ Cm, const float* __restrict__ W1,
    const float* __restrict__ b1, const float* __restrict__ W_ih,
    const float* __restrict__ W_hh, const float* __restrict__ b_ih,
    const float* __restrict__ b_hh, const float* __restrict__ W2,
    const float* __restrict__ b2, const float* __restrict__ W3,
    const float* __restrict__ b3, float* __restrict__ out,
    float* __restrict__ ws)
{
  cg::grid_group grid = cg::this_grid();
  const int tid = threadIdx.x, lane = tid & 63, wav = tid >> 6, bid = blockIdx.x;
  const int gt = bid * 256 + tid, wave_g = bid * 4 + wav, NW = gridDim.x * 4;

  __shared__ __align__(16) float4 s_buf4[1040];
  __shared__ __align__(16) float4 s_h4[580];
  __shared__ __align__(16) float s_kgin[52];
  __shared__ float s_innov[48];
  __shared__ float s_xpost[4], s_xprior[4], s_dx[4];
  __shared__ float s_sc2, s_sc4;

  for (int t = 0; t <= T_STEPS; ++t) {
    if (t == 0) {
      if (tid < 4) s_xpost[tid] = x0[tid];
    } else {
      const float4* vv  = (const float4*)(ws + WS_V + wav * 768);
      const float4* l2v = (const float4*)(ws + WS_L2);
      float acc = 0.f;
      for (int k = lane; k < 192; k += 64) acc += dot4(vv[k], l2v[k]);
      acc = wred(acc);
      if (lane == 0)
        s_xpost[wav] = s_xprior[wav] + (acc + ws[WS_C + wav]) * 1e-4f;
    }
    __syncthreads();
    if (bid == 0 && t > 0 && tid < 4) out[tid * T_STEPS + (t - 1)] = s_xpost[tid];
    if (t == T_STEPS) return;

    if (tid < 4) {
      float xp = 0.f;
#pragma unroll
      for (int j = 0; j < 4; j++) xp += A[tid * 4 + j] * s_xpost[j];
      s_xprior[tid] = xp;
    }
    __syncthreads();
    if (tid < 48) {
      float yp = Cm[tid * 5 + 4];
#pragma unroll
      for (int j = 0; j < 4; j++) yp += Cm[tid * 5 + j] * s_xprior[j];
      s_innov[tid] = y_seq[tid * T_STEPS + t] - yp;
    }
    if (tid >= 64 && tid < 68) {
      int i = tid - 64;
      s_dx[i] = s_xpost[i] - s_xprior[i];
    }
    __syncthreads();
    if (tid == 0) {
      float s2 = 0.f;
      for (int r = 0; r < 48; r++) s2 += s_innov[r] * s_innov[r];
      s_sc2 = 1.0f / fmaxf(sqrtf(s2), 1e-12f);
      float s4 = 0.f;
      for (int i = 0; i < 4; i++) s4 += s_dx[i] * s_dx[i];
      s_sc4 = 1.0f / fmaxf(sqrtf(s4), 1e-12f);
    }
    __syncthreads();
    if (tid < 48) s_kgin[tid] = s_innov[tid] * s_sc2;
    else if (tid < 52) s_kgin[tid] = s_dx[tid - 48] * s_sc4;
    __syncthreads();

    if (gt < 4160) {
      const float4* wr  = (const float4*)(W1 + (size_t)gt * 52);
      const float4* kg4 = (const float4*)s_kgin;
      float acc = b1[gt];
#pragma unroll
      for (int k = 0; k < 13; k++) acc += dot4(wr[k], kg4[k]);
      ws[WS_L1 + gt] = fmaxf(acc, 0.f);
    }
    grid.sync();

    {
      const float* h_old = (t == 0) ? h0 : (ws + (((t & 1) == 0) ? WS_H0 : WS_H1));
      float* h_new = ws + (((t & 1) == 0) ? WS_H1 : WS_H0);
      const float4* l1g = (const float4*)(ws + WS_L1);
      for (int i = tid; i < 1040; i += 256) s_buf4[i] = l1g[i];
      const float4* hog = (const float4*)h_old;
      for (int i = tid; i < 580; i += 256) s_h4[i] = hog[i];
      __syncthreads();
      const float* s_h = (const float*)s_h4;

      for (int j = wave_g; j < 2320; j += NW) {
        const float4* r0 = (const float4*)(W_ih + (size_t)j * 4160);
        const float4* r1 = (const float4*)(W_ih + (size_t)(j + 2320) * 4160);
        const float4* r2 = (const float4*)(W_ih + (size_t)(j + 4640) * 4160);
        float a0 = 0.f, a1 = 0.f, a2 = 0.f;
#pragma unroll 4
        for (int k = lane; k < 1040; k += 64) {
          float4 x = s_buf4[k];
          a0 += dot4(r0[k], x); a1 += dot4(r1[k], x); a2 += dot4(r2[k], x);
        }
        const float4* q0 = (const float4*)(W_hh + (size_t)j * 2320);
        const float4* q1 = (const float4*)(W_hh + (size_t)(j + 2320) * 2320);
        const float4* q2 = (const float4*)(W_hh + (size_t)(j + 4640) * 2320);
        float c0 = 0.f, c1 = 0.f, c2 = 0.f;
#pragma unroll 4
        for (int k = lane; k < 580; k += 64) {
          float4 x = s_h4[k];
          c0 += dot4(q0[k], x); c1 += dot4(q1[k], x); c2 += dot4(q2[k], x);
        }
        a0 = wred(a0); a1 = wred(a1); a2 = wred(a2);
        c0 = wred(c0); c1 = wred(c1); c2 = wred(c2);
        if (lane == 0) {
          float ir = a0 + b_ih[j], iz = a1 + b_ih[j + 2320], ig = a2 + b_ih[j + 4640];
          float hr = c0 + b_hh[j], hz = c1 + b_hh[j + 2320], hg = c2 + b_hh[j + 4640];
          float rr = 1.f / (1.f + expf(-(ir + hr)));
          float zz = 1.f / (1.f + expf(-(iz + hz)));
          float gg = tanhf(ig + rr * hg);
          h_new[j] = (1.f - zz) * gg + zz * s_h[j];
        }
      }
    }
    grid.sync();

    {
      const float* h_new = ws + (((t & 1) == 0) ? WS_H1 : WS_H0);
      const float4* hv = (const float4*)h_new;
      for (int i = tid; i < 580; i += 256) s_buf4[i] = hv[i];
      __syncthreads();

      if (gt < 3072) {
        int i = gt / 768, cc = gt - i * 768;
        const float* wcol = W3 + (size_t)(i * 48) * 768 + cc;
        float acc = 0.f;
#pragma unroll 8
        for (int j = 0; j < 48; j++) acc += s_innov[j] * wcol[(size_t)j * 768];
        ws[WS_V + gt] = acc;
      } else if (gt < 3076) {
        int i = gt - 3072;
        float acc = 0.f;
        for (int j = 0; j < 48; j++) acc += s_innov[j] * b3[i * 48 + j];
        ws[WS_C + i] = acc;
      }

      for (int task = wave_g; task < 768; task += NW) {
        const float4* row = (const float4*)(W2 + (size_t)task * 2320);
        float acc = 0.f;
#pragma unroll 4
        for (int k = lane; k < 580; k += 64) acc += dot4(row[k], s_buf4[k]);
        acc = wred(acc);
        if (lane == 0) ws[WS_L2 + task] = fmaxf(acc + b2[task], 0.f);
      }
    }
    grid.sync();
  }
}

extern "C" void kernel_launch(void* const* d_in, const int* in_sizes, int n_in,
                              void* d_out, int out_size, void* d_ws, size_t ws_size,
                              hipStream_t stream) {
  const float* y_seq = (const float*)d_in[0];
  const float* x0    = (const float*)d_in[1];
  const float* h0    = (const float*)d_in[2];
  const float* A     = (const float*)d_in[3];
  const float* Cm    = (const float*)d_in[4];
  const float* W1    = (const float*)d_in[5];
  const float* b1    = (const float*)d_in[6];
  const float* W_ih  = (const float*)d_in[7];
  const float* W_hh  = (const float*)d_in[8];
  const float* b_ih  = (const float*)d_in[9];
  const float* b_hh  = (const float*)d_in[10];
  const float* W2    = (const float*)d_in[11];
  const float* b2    = (const float*)d_in[12];
  const float* W3    = (const float*)d_in[13];
  const float* b3    = (const float*)d_in[14];
  float* out = (float*)d_out;
  float* ws  = (float*)d_ws;
  char* wsb  = (char*)d_ws;

  if (ws_size >= NEED_MIN) {
    int use_w1p = (ws_size >= NEED_FULL) ? 1 : 0;
    // allow 130 KB dynamic LDS (persists device-wide after first uncaptured call)
    hipFuncSetAttribute(reinterpret_cast<const void*>(knet2),
                        hipFuncAttributeMaxDynamicSharedMemorySize, DYN_LDS + 2048);
    hipMemsetAsync(wsb + O_SLOT, 0, 2048, stream);   // slots + epoch
    k_pack<<<8192, 256, 0, stream>>>(W_ih, (uint4*)(wsb + O_PIH),
                                     4160, 130, 435 * 130 * 64);
    k_pack<<<8192, 256, 0, stream>>>(W_hh, (uint4*)(wsb + O_PHH),
                                     2320, 73, 435 * 73 * 64);
    k_cvt<<<512, 256, 0, stream>>>((const float4*)W2,
                                   (ushort4*)(wsb + O_W2B), N_W2 / 4);
    if (use_w1p)
      k_cvtw1<<<(4160 * 56 + 255) / 256, 256, 0, stream>>>(
          W1, (unsigned short*)(wsb + O_W1P));
    k_h0<<<10, 256, 0, stream>>>(h0, (unsigned short*)(wsb + O_HB),
                                 (unsigned short*)(wsb + O_HB + HB_STR));

    void* args[] = { &y_seq, &x0, &h0, &A, &Cm, &W1, &b1, &b_ih, &b_hh,
                     &b2, &W3, &b3, &out, &wsb, &use_w1p };
    hipError_t err = hipLaunchCooperativeKernel(
        reinterpret_cast<void*>(knet2), dim3(256), dim3(1024), args, DYN_LDS, stream);
    if (err == hipSuccess) return;
  }

  {
    void* args[] = { &y_seq, &x0, &h0, &A, &Cm, &W1, &b1, &W_ih, &W_hh,
                     &b_ih, &b_hh, &W2, &b2, &W3, &b3, &out, &ws };
    hipLaunchCooperativeKernel(
        reinterpret_cast<void*>(knet), dim3(256), dim3(256), args, 0, stream);
  }
}

// Round 13
// 10333.331 us; speedup vs baseline: 3.5170x; 1.0373x over previous
//
#include <hip/hip_runtime.h>
#include <hip/hip_cooperative_groups.h>

namespace cg = cooperative_groups;

#define T_STEPS 256
// sizes: M=4 N=48 H1=4160 HID=2320 3HID=6960 H2=768 OUT=192 KGIN=52

// ---------------- ws byte-offset layout ----------------
#define O_SLOT  0                  // 256 u32 arrival slots
#define O_EPOCH 1024               // 1 u32 epoch
#define O_ZP    2048               // 96*4 f32 z-partials
#define O_HF    6144               // 2 x 2320 f32 (h state, parity)
#define HF_STR  9280               // ends 24704
#define O_HB    24704              // 2 x 2336 bf16 (h bf16, parity)
#define HB_STR  4672               // ends 34048
#define O_GI4   34048              // 2320*4 f32 interleaved (r,z,g,pad)
#define O_GH4   71168              // 2320*4 f32 -> ends 108288
// packed weights: pk[job][kt][lane] 16B fragments, per-wave contiguous streams
#define O_PIH   108544             // 435 jobs * 130 kt * 1024B = 57,907,200
#define O_PHH   58015744           // 435 jobs *  73 kt * 1024B = 32,517,120
#define O_W2B   90532864           // 768*2320 bf16 row-major   =  3,563,520
#define NEED_MIN 94096384
#define O_W1P   94096384           // 4160*56 bf16 (padded W1)  =    465,920
#define NEED_FULL 94562304

#define N_W2  1781760
#define PIN_U4 (130 * 64)          // 8320 uint4 = 133,120 B pinned per block
#define DYN_LDS 133120

// legacy fp32-path offsets (float units) for fallback kernel
#define WS_L1  0
#define WS_H0  4160
#define WS_H1  6480
#define WS_L2  8800
#define WS_V   9568
#define WS_C   12640

typedef __attribute__((ext_vector_type(8))) short bf16x8;
typedef __attribute__((ext_vector_type(4))) float f32x4;
typedef unsigned long long u64t;

__device__ __forceinline__ float wred(float v) {
#pragma unroll
  for (int m = 32; m; m >>= 1) v += __shfl_xor(v, m, 64);
  return v;
}
__device__ __forceinline__ float dot4(float4 a, float4 b) {
  return a.x * b.x + a.y * b.y + a.z * b.z + a.w * b.w;
}
__device__ __forceinline__ float blo(unsigned u) {
  unsigned t = u << 16; return __builtin_bit_cast(float, t);
}
__device__ __forceinline__ float bhi(unsigned u) {
  unsigned t = u & 0xFFFF0000u; return __builtin_bit_cast(float, t);
}
__device__ __forceinline__ float dot8bb(uint4 w, uint4 x) {
  float s;
  s  = blo(w.x) * blo(x.x) + bhi(w.x) * bhi(x.x);
  s += blo(w.y) * blo(x.y) + bhi(w.y) * bhi(x.y);
  s += blo(w.z) * blo(x.z) + bhi(w.z) * bhi(x.z);
  s += blo(w.w) * blo(x.w) + bhi(w.w) * bhi(x.w);
  return s;
}
__device__ __forceinline__ unsigned short f2bf(float f) {  // RNE
  unsigned u = __builtin_bit_cast(unsigned, f);
  unsigned r = u + 0x7FFF + ((u >> 16) & 1);
  return (unsigned short)(r >> 16);
}
__device__ __forceinline__ float u2f_lo(u64t v) {
  unsigned u = (unsigned)(v & 0xFFFFFFFFull);
  return __builtin_bit_cast(float, u);
}
__device__ __forceinline__ float u2f_hi(u64t v) {
  unsigned u = (unsigned)(v >> 32);
  return __builtin_bit_cast(float, u);
}

// ---- scoped accessors: cross-block data via coherence point, no invalidates
__device__ __forceinline__ void st_ag_f32(float* p, float v) {
  __hip_atomic_store(p, v, __ATOMIC_RELAXED, __HIP_MEMORY_SCOPE_AGENT);
}
__device__ __forceinline__ float ld_ag_f32(const float* p) {
  return __hip_atomic_load(p, __ATOMIC_RELAXED, __HIP_MEMORY_SCOPE_AGENT);
}
__device__ __forceinline__ void st_ag_u32(unsigned* p, unsigned v) {
  __hip_atomic_store(p, v, __ATOMIC_RELAXED, __HIP_MEMORY_SCOPE_AGENT);
}
__device__ __forceinline__ u64t ld_ag_u64(const u64t* p) {
  return __hip_atomic_load(p, __ATOMIC_RELAXED, __HIP_MEMORY_SCOPE_AGENT);
}

// ---------- slot barrier (R11-proven): parallel release-store arrivals ----------
__device__ __forceinline__ void gbar(char* wsb, int bid, unsigned target, int* s_ok) {
  unsigned* slot  = (unsigned*)(wsb + O_SLOT);
  unsigned* epoch = (unsigned*)(wsb + O_EPOCH);
  const int tid = threadIdx.x;
  __syncthreads();
  if (bid == 0) {
    for (;;) {
      if (tid == 0) *s_ok = 1;
      __syncthreads();
      if (tid >= 1 && tid < 256) {
        if (__hip_atomic_load(&slot[tid], __ATOMIC_RELAXED, __HIP_MEMORY_SCOPE_AGENT) < target)
          *s_ok = 0;
      }
      __syncthreads();
      if (*s_ok) break;
      __builtin_amdgcn_s_sleep(2);
    }
    if (tid == 0)
      __hip_atomic_store(epoch, target, __ATOMIC_RELEASE, __HIP_MEMORY_SCOPE_AGENT);
    __syncthreads();
  } else {
    if (tid == 0) {
      __hip_atomic_store(&slot[bid], target, __ATOMIC_RELEASE, __HIP_MEMORY_SCOPE_AGENT);
      while (__hip_atomic_load(epoch, __ATOMIC_RELAXED, __HIP_MEMORY_SCOPE_AGENT) < target)
        __builtin_amdgcn_s_sleep(1);
    }
    __syncthreads();
  }
}

// ---------------- pre-pass kernels ----------------
__global__ __launch_bounds__(256) void k_pack(const float* __restrict__ W,
                                              uint4* __restrict__ dst,
                                              int K, int NKT, int n) {
  int idx = blockIdx.x * 256 + threadIdx.x;
  int stride = gridDim.x * 256;
  for (; idx < n; idx += stride) {
    int l = idx & 63;
    int u = idx >> 6;
    int kt = u % NKT;
    int job = u / NKT;
    int g = job / 145, jt = job - g * 145;
    int row = g * 2320 + jt * 16 + (l & 15);
    int col = kt * 32 + ((l >> 4) << 3);
    const float* src = W + (size_t)row * K + col;
    unsigned short o[8];
    if (col + 7 < K) {
#pragma unroll
      for (int i = 0; i < 8; i++) o[i] = f2bf(src[i]);
    } else {
#pragma unroll
      for (int i = 0; i < 8; i++) o[i] = (col + i < K) ? f2bf(src[i]) : (unsigned short)0;
    }
    uint4 v;
    v.x = (unsigned)o[0] | ((unsigned)o[1] << 16);
    v.y = (unsigned)o[2] | ((unsigned)o[3] << 16);
    v.z = (unsigned)o[4] | ((unsigned)o[5] << 16);
    v.w = (unsigned)o[6] | ((unsigned)o[7] << 16);
    dst[idx] = v;
  }
}
__global__ __launch_bounds__(256) void k_cvt(const float4* __restrict__ src,
                                             ushort4* __restrict__ dst, int n4) {
  int i = blockIdx.x * 256 + threadIdx.x, st = gridDim.x * 256;
  for (; i < n4; i += st) {
    float4 v = src[i];
    ushort4 o;
    o.x = f2bf(v.x); o.y = f2bf(v.y); o.z = f2bf(v.z); o.w = f2bf(v.w);
    dst[i] = o;
  }
}
__global__ __launch_bounds__(256) void k_cvtw1(const float* __restrict__ W1,
                                               unsigned short* __restrict__ dst) {
  int i = blockIdx.x * 256 + threadIdx.x;           // over 4160*56
  if (i < 4160 * 56) {
    int r = i / 56, c = i - r * 56;
    dst[i] = (c < 52) ? f2bf(W1[r * 52 + c]) : (unsigned short)0;
  }
}
__global__ __launch_bounds__(256) void k_h0(const float* __restrict__ h0,
                                            unsigned short* __restrict__ hb0,
                                            unsigned short* __restrict__ hb1) {
  int j = blockIdx.x * 256 + threadIdx.x;
  if (j < 2336) {
    hb1[j] = (j < 2320) ? f2bf(h0[j]) : (unsigned short)0;
    if (j >= 2320) hb0[j] = 0;
  }
}

// ================= main 2-sync kernel (256 blocks x 1024 threads) =================
// R13: single change vs R12 — CLAMP the 8-deep prefetch refill index to the
// chunk's last valid unit. The old refill read 8 units past kend per wave =
// 24.6 MB/step of junk fetch (60% of FETCH_SIZE; also explains R9's 16-deep
// regression: 2x junk). Clamped refill re-reads an L1-hot line instead.
// Consumed values unchanged -> numerics bit-identical (absmax 0.125 exact).
__global__ __launch_bounds__(1024, 4) void knet2(
    const float* __restrict__ y_seq, const float* __restrict__ x0,
    const float* __restrict__ h0, const float* __restrict__ A,
    const float* __restrict__ Cm, const float* __restrict__ W1,
    const float* __restrict__ b1, const float* __restrict__ b_ih,
    const float* __restrict__ b_hh, const float* __restrict__ b2,
    const float* __restrict__ W3, const float* __restrict__ b3,
    float* __restrict__ out, char* __restrict__ wsb, int use_w1p)
{
  const int tid  = threadIdx.x;
  const int lane = tid & 63;
  const int wav  = tid >> 6;
  const int bid  = blockIdx.x;

  float* zp  = (float*)(wsb + O_ZP);
  float* gi4 = (float*)(wsb + O_GI4);
  float* gh4 = (float*)(wsb + O_GH4);
  const unsigned short* bw2 = (const unsigned short*)(wsb + O_W2B);
  const uint4* w1p = (const uint4*)(wsb + O_W1P);

  extern __shared__ __align__(16) char dynsmem[];
  uint4* pin = (uint4*)dynsmem;                  // 130 kt x 64 lanes, q0 job

  __shared__ __align__(16) uint4 s_l1u[520];     // l1 bf16
  __shared__ __align__(16) uint4 s_h4u[292];     // h bf16 (MFMA operand)
  __shared__ __align__(16) unsigned short s_h2[2336];  // h_new bf16 (C)
  __shared__ float s_part[4][4][16];
  __shared__ __align__(16) unsigned short s_kgb[64];
  __shared__ __align__(16) float s_kgf[52];
  __shared__ float s_innov[48];
  __shared__ float s_a[192];
  __shared__ float s_zred[384];
  __shared__ float s_l2loc[8];
  __shared__ float s_xpost[4], s_xprior[4], s_dx[4];
  __shared__ float s_sc2, s_sc4;
  __shared__ int s_ok;

  // ---- one-time: pin this block's q0 (ih) job weights into LDS ----
  {
    const uint4* src = (const uint4*)(wsb + O_PIH) + (size_t)bid * PIN_U4;
    for (int i = tid; i < PIN_U4; i += 1024) pin[i] = src[i];
  }

  unsigned ep = 0;

  for (int t = 0; t <= T_STEPS; ++t) {
    // ======== prologue: x_post(t) from z-partials(t-1) [all blocks] ========
    if (t == 0) {
      if (tid < 4) s_xpost[tid] = x0[tid];
    } else {
      if (tid < 384) s_zred[tid] = ld_ag_f32(&zp[tid]);   // parallel gather
      __syncthreads();
      if (tid < 4) {
        float z = 0.f;
#pragma unroll 8
        for (int p = 0; p < 96; ++p) z += s_zred[p * 4 + tid];
        float cb = 0.f;
        for (int j = 0; j < 48; ++j) cb += s_innov[j] * b3[tid * 48 + j];
        float xn = s_xprior[tid] + (z + cb) * 1e-4f;
        s_xpost[tid] = xn;
        if (bid == 0) out[tid * T_STEPS + (t - 1)] = xn;
      }
    }
    __syncthreads();
    if (t == T_STEPS) return;

    // ======== small math: x_prior, innov, kg_in ========
    if (tid < 4) {
      float xpr = 0.f;
#pragma unroll
      for (int j = 0; j < 4; j++) xpr += A[tid * 4 + j] * s_xpost[j];
      s_xprior[tid] = xpr;
    }
    __syncthreads();
    if (tid < 48) {
      float yp = Cm[tid * 5 + 4];
#pragma unroll
      for (int j = 0; j < 4; j++) yp += Cm[tid * 5 + j] * s_xprior[j];
      s_innov[tid] = y_seq[tid * T_STEPS + t] - yp;
    }
    if (tid >= 64 && tid < 68) {
      int i = tid - 64;
      s_dx[i] = s_xpost[i] - s_xprior[i];
    }
    __syncthreads();
    if (tid == 0) {
      float s2 = 0.f;
      for (int r = 0; r < 48; r++) s2 += s_innov[r] * s_innov[r];
      s_sc2 = 1.0f / fmaxf(sqrtf(s2), 1e-12f);
      float s4 = 0.f;
      for (int i = 0; i < 4; i++) s4 += s_dx[i] * s_dx[i];
      s_sc4 = 1.0f / fmaxf(sqrtf(s4), 1e-12f);
    }
    __syncthreads();
    if (tid < 64) {
      float v = (tid < 48) ? s_innov[tid] * s_sc2
              : (tid < 52) ? s_dx[tid - 48] * s_sc4 : 0.f;
      s_kgb[tid] = f2bf(v);
      if (tid < 52) s_kgf[tid] = v;
    }
    // stage h(t-1) bf16 into LDS via agent loads
    {
      const u64t* hbg = (const u64t*)(wsb + O_HB + ((t + 1) & 1) * HB_STR);
      u64t* dst = (u64t*)s_h4u;
      if (tid < 584) dst[tid] = ld_ag_u64(hbg + tid);
    }
    __syncthreads();

    // ======== l1 = relu(W1 @ kg + b1), redundant per block ========
    if (use_w1p) {
      const uint4* kg4 = (const uint4*)s_kgb;
      for (int r = tid; r < 4160; r += 1024) {
        const uint4* wr = w1p + (size_t)r * 7;
        float acc = b1[r];
#pragma unroll
        for (int c = 0; c < 7; c++) acc += dot8bb(wr[c], kg4[c]);
        ((unsigned short*)s_l1u)[r] = f2bf(fmaxf(acc, 0.f));
      }
    } else {
      const float4* kg4 = (const float4*)s_kgf;
      for (int r = tid; r < 4160; r += 1024) {
        const float4* wr = (const float4*)(W1 + (size_t)r * 52);
        float acc = b1[r];
#pragma unroll
        for (int c = 0; c < 13; c++) acc += dot4(wr[c], kg4[c]);
        ((unsigned short*)s_l1u)[r] = f2bf(fmaxf(acc, 0.f));
      }
    }
    __syncthreads();

    // ======== GRU GEMV via MFMA: q0 pinned LDS; q1-3 global 8-deep CLAMPED ====
    {
      const int q  = wav >> 2;        // job slot 0..3
      const int kw = wav & 3;         // k-split
      const int job = bid + 256 * q;
      if (job < 870) {
        const int xoff = lane >> 4;
        f32x4 acc = {0.f, 0.f, 0.f, 0.f};
        if (q == 0) {
          // ---- pinned LDS path (ih job 'bid', all 130 kt resident) ----
          int kbeg = kw * 33, kend = kbeg + 33; if (kend > 130) kend = 130;
          const uint4* xs = s_l1u;
          for (int kt = kbeg; kt < kend; ++kt)
            acc = __builtin_amdgcn_mfma_f32_16x16x32_bf16(
                __builtin_bit_cast(bf16x8, pin[kt * 64 + lane]),
                __builtin_bit_cast(bf16x8, xs[kt * 4 + xoff]), acc, 0, 0, 0);
        } else {
          const int side = (job < 435) ? 0 : 1;
          const uint4* xs;
          const uint4* wp;
          int kbeg, kend;
          if (side == 0) {
            xs = s_l1u;
            kbeg = kw * 33; kend = kbeg + 33; if (kend > 130) kend = 130;
            wp = (const uint4*)(wsb + O_PIH) + ((size_t)job * 130 + kbeg) * 64 + lane;
          } else {
            xs = s_h4u;
            kbeg = kw * 19; kend = kbeg + 19; if (kend > 73) kend = 73;
            wp = (const uint4*)(wsb + O_PHH) + ((size_t)(job - 435) * 73 + kbeg) * 64 + lane;
          }
          const int last = kend - kbeg - 1;   // last valid local unit
          uint4 b0  = wp[0 * 64];
          uint4 b1r = wp[1 * 64];
          uint4 b2r = wp[2 * 64];
          uint4 b3r = wp[3 * 64];
          uint4 b4  = wp[4 * 64];
          uint4 b5  = wp[5 * 64];
          uint4 b6  = wp[6 * 64];
          uint4 b7  = wp[7 * 64];
          int kt = kbeg;
#define GSTEP(P, B) { acc = __builtin_amdgcn_mfma_f32_16x16x32_bf16( \
              __builtin_bit_cast(bf16x8, B), \
              __builtin_bit_cast(bf16x8, xs[(kt + P) * 4 + xoff]), acc, 0, 0, 0); \
              int ri = kt - kbeg + 8 + P; ri = (ri > last) ? last : ri; \
              B = wp[(size_t)ri * 64]; }
          while (kt + 8 <= kend) {
            GSTEP(0, b0) GSTEP(1, b1r) GSTEP(2, b2r) GSTEP(3, b3r)
            GSTEP(4, b4) GSTEP(5, b5)  GSTEP(6, b6)  GSTEP(7, b7)
            kt += 8;
          }
#undef GSTEP
#define TSTEP(P, B) if (kt + P < kend) acc = __builtin_amdgcn_mfma_f32_16x16x32_bf16( \
              __builtin_bit_cast(bf16x8, B), \
              __builtin_bit_cast(bf16x8, xs[(kt + P) * 4 + xoff]), acc, 0, 0, 0);
          TSTEP(0, b0) TSTEP(1, b1r) TSTEP(2, b2r) TSTEP(3, b3r)
          TSTEP(4, b4) TSTEP(5, b5)  TSTEP(6, b6)  TSTEP(7, b7)
#undef TSTEP
        }
        if ((lane & 15) == 0) {
          int rb = (lane >> 4) * 4;
#pragma unroll
          for (int i = 0; i < 4; i++) s_part[q][kw][rb + i] = acc[i];
        }
      }
    }
    __syncthreads();
    if (tid < 64) {
      int q = tid >> 4, r = tid & 15;
      int job = bid + 256 * q;
      if (job < 870) {
        float s = s_part[q][0][r] + s_part[q][1][r] + s_part[q][2][r] + s_part[q][3][r];
        if (job < 435) {
          int g = job / 145, jt = job - g * 145;
          st_ag_f32(&gi4[(size_t)(jt * 16 + r) * 4 + g], s);
        } else {
          int j2 = job - 435;
          int g = j2 / 145, jt = j2 - g * 145;
          st_ag_f32(&gh4[(size_t)(jt * 16 + r) * 4 + g], s);
        }
      }
    }
    ++ep; gbar(wsb, bid, ep, &s_ok);   // -------- SYNC 1: gi/gh ready --------

    // ======== C: gates (96 blocks, redundant), l2, z-partials ========
    if (bid < 96) {
      float* hf_out = (float*)(wsb + O_HF + (t & 1) * HF_STR);
      unsigned* hb_out32 = (unsigned*)(wsb + O_HB + (t & 1) * HB_STR);
      const float* hf_old = (const float*)(wsb + O_HF + ((t + 1) & 1) * HF_STR);
      const u64t* gi2 = (const u64t*)gi4;
      const u64t* gh2 = (const u64t*)gh4;
      for (int j = tid; j < 2320; j += 1024) {
        u64t ia = ld_ag_u64(&gi2[(size_t)j * 2]);
        u64t ib = ld_ag_u64(&gi2[(size_t)j * 2 + 1]);
        u64t ha = ld_ag_u64(&gh2[(size_t)j * 2]);
        u64t hb = ld_ag_u64(&gh2[(size_t)j * 2 + 1]);
        float ir = u2f_lo(ia) + b_ih[j];
        float iz = u2f_hi(ia) + b_ih[2320 + j];
        float ig = u2f_lo(ib) + b_ih[4640 + j];
        float hr = u2f_lo(ha) + b_hh[j];
        float hz = u2f_hi(ha) + b_hh[2320 + j];
        float hg = u2f_lo(hb) + b_hh[4640 + j];
        float rr = 1.f / (1.f + expf(-(ir + hr)));
        float zz = 1.f / (1.f + expf(-(iz + hz)));
        float gg = tanhf(ig + rr * hg);
        float hold = (t == 0) ? h0[j] : ld_ag_f32(&hf_old[j]);
        float hn = (1.f - zz) * gg + zz * hold;
        s_h2[j] = f2bf(hn);
        if (bid == 0) st_ag_f32(&hf_out[j], hn);
      }
      if (tid < 16) s_h2[2320 + tid] = 0;   // keep K-pad zero
      __syncthreads();
      // publish h_new bf16 (bid 0 only), packed u32 agent stores
      if (bid == 0 && tid < 1168) {
        unsigned v = (unsigned)s_h2[2 * tid] | ((unsigned)s_h2[2 * tid + 1] << 16);
        st_ag_u32(hb_out32 + tid, v);
      }
      // l2 rows (8 per block), bf16 VALU dot from LDS
      if (wav < 8) {
        const int row = bid * 8 + wav;
        const uint4* wr = (const uint4*)(bw2 + (size_t)row * 2320);
        const uint4* hx = (const uint4*)s_h2;
        float acc = 0.f;
        for (int k = lane; k < 290; k += 64) acc += dot8bb(wr[k], hx[k]);
        acc = wred(acc);
        if (lane == 0) s_l2loc[wav] = fmaxf(acc + b2[row], 0.f);
      }
      __syncthreads();
      // z-partials
      if (tid < 192) {
        const float* w3r = W3 + (size_t)tid * 768 + bid * 8;
        float a = 0.f;
#pragma unroll
        for (int r = 0; r < 8; r++) a += w3r[r] * s_l2loc[r];
        s_a[tid] = a * s_innov[tid % 48];
      }
      __syncthreads();
      if (tid < 4) {
        float zv = 0.f;
        for (int j = 0; j < 48; j++) zv += s_a[tid * 48 + j];
        st_ag_f32(&zp[bid * 4 + tid], zv);
      }
    }
    ++ep; gbar(wsb, bid, ep, &s_ok);   // -------- SYNC 2: h/l2/z ready --------
  }
}

// ================= cooperative fp32 kernel (proven fallback) =================
__global__ __launch_bounds__(256, 2) void knet(
    const float* __restrict__ y_seq, const float* __restrict__ x0,
    const float* __restrict__ h0, const float* __restrict__ A,
    const float* __restrict__ Cm, const float* __restrict__ W1,
    const float* __restrict__ b1, const float* __restrict__ W_ih,
    const float* __restrict__ W_hh, const float* __restrict__ b_ih,
    const float* __restrict__ b_hh, const float* __restrict__ W2,
    const float* __restrict__ b2, const float* __restrict__ W3,
    const float* __restrict__ b3, float* __restrict__ out,
    float* __restrict__ ws)
{
  cg::grid_group grid = cg::this_grid();
  const int tid = threadIdx.x, lane = tid & 63, wav = tid >> 6, bid = blockIdx.x;
  const int gt = bid * 256 + tid, wave_g = bid * 4 + wav, NW = gridDim.x * 4;

  __shared__ __align__(16) float4 s_buf4[1040];
  __shared__ __align__(16) float4 s_h4[580];
  __shared__ __align__(16) float s_kgin[52];
  __shared__ float s_innov[48];
  __shared__ float s_xpost[4], s_xprior[4], s_dx[4];
  __shared__ float s_sc2, s_sc4;

  for (int t = 0; t <= T_STEPS; ++t) {
    if (t == 0) {
      if (tid < 4) s_xpost[tid] = x0[tid];
    } else {
      const float4* vv  = (const float4*)(ws + WS_V + wav * 768);
      const float4* l2v = (const float4*)(ws + WS_L2);
      float acc = 0.f;
      for (int k = lane; k < 192; k += 64) acc += dot4(vv[k], l2v[k]);
      acc = wred(acc);
      if (lane == 0)
        s_xpost[wav] = s_xprior[wav] + (acc + ws[WS_C + wav]) * 1e-4f;
    }
    __syncthreads();
    if (bid == 0 && t > 0 && tid < 4) out[tid * T_STEPS + (t - 1)] = s_xpost[tid];
    if (t == T_STEPS) return;

    if (tid < 4) {
      float xp = 0.f;
#pragma unroll
      for (int j = 0; j < 4; j++) xp += A[tid * 4 + j] * s_xpost[j];
      s_xprior[tid] = xp;
    }
    __syncthreads();
    if (tid < 48) {
      float yp = Cm[tid * 5 + 4];
#pragma unroll
      for (int j = 0; j < 4; j++) yp += Cm[tid * 5 + j] * s_xprior[j];
      s_innov[tid] = y_seq[tid * T_STEPS + t] - yp;
    }
    if (tid >= 64 && tid < 68) {
      int i = tid - 64;
      s_dx[i] = s_xpost[i] - s_xprior[i];
    }
    __syncthreads();
    if (tid == 0) {
      float s2 = 0.f;
      for (int r = 0; r < 48; r++) s2 += s_innov[r] * s_innov[r];
      s_sc2 = 1.0f / fmaxf(sqrtf(s2), 1e-12f);
      float s4 = 0.f;
      for (int i = 0; i < 4; i++) s4 += s_dx[i] * s_dx[i];
      s_sc4 = 1.0f / fmaxf(sqrtf(s4), 1e-12f);
    }
    __syncthreads();
    if (tid < 48) s_kgin[tid] = s_innov[tid] * s_sc2;
    else if (tid < 52) s_kgin[tid] = s_dx[tid - 48] * s_sc4;
    __syncthreads();

    if (gt < 4160) {
      const float4* wr  = (const float4*)(W1 + (size_t)gt * 52);
      const float4* kg4 = (const float4*)s_kgin;
      float acc = b1[gt];
#pragma unroll
      for (int k = 0; k < 13; k++) acc += dot4(wr[k], kg4[k]);
      ws[WS_L1 + gt] = fmaxf(acc, 0.f);
    }
    grid.sync();

    {
      const float* h_old = (t == 0) ? h0 : (ws + (((t & 1) == 0) ? WS_H0 : WS_H1));
      float* h_new = ws + (((t & 1) == 0) ? WS_H1 : WS_H0);
      const float4* l1g = (const float4*)(ws + WS_L1);
      for (int i = tid; i < 1040; i += 256) s_buf4[i] = l1g[i];
      const float4* hog = (const float4*)h_old;
      for (int i = tid; i < 580; i += 256) s_h4[i] = hog[i];
      __syncthreads();
      const float* s_h = (const float*)s_h4;

      for (int j = wave_g; j < 2320; j += NW) {
        const float4* r0 = (const float4*)(W_ih + (size_t)j * 4160);
        const float4* r1 = (const float4*)(W_ih + (size_t)(j + 2320) * 4160);
        const float4* r2 = (const float4*)(W_ih + (size_t)(j + 4640) * 4160);
        float a0 = 0.f, a1 = 0.f, a2 = 0.f;
#pragma unroll 4
        for (int k = lane; k < 1040; k += 64) {
          float4 x = s_buf4[k];
          a0 += dot4(r0[k], x); a1 += dot4(r1[k], x); a2 += dot4(r2[k], x);
        }
        const float4* q0 = (const float4*)(W_hh + (size_t)j * 2320);
        const float4* q1 = (const float4*)(W_hh + (size_t)(j + 2320) * 2320);
        const float4* q2 = (const float4*)(W_hh + (size_t)(j + 4640) * 2320);
        float c0 = 0.f, c1 = 0.f, c2 = 0.f;
#pragma unroll 4
        for (int k = lane; k < 580; k += 64) {
          float4 x = s_h4[k];
          c0 += dot4(q0[k], x); c1 += dot4(q1[k], x); c2 += dot4(q2[k], x);
        }
        a0 = wred(a0); a1 = wred(a1); a2 = wred(a2);
        c0 = wred(c0); c1 = wred(c1); c2 = wred(c2);
        if (lane == 0) {
          float ir = a0 + b_ih[j], iz = a1 + b_ih[j + 2320], ig = a2 + b_ih[j + 4640];
          float hr = c0 + b_hh[j], hz = c1 + b_hh[j + 2320], hg = c2 + b_hh[j + 4640];
          float rr = 1.f / (1.f + expf(-(ir + hr)));
          float zz = 1.f / (1.f + expf(-(iz + hz)));
          float gg = tanhf(ig + rr * hg);
          h_new[j] = (1.f - zz) * gg + zz * s_h[j];
        }
      }
    }
    grid.sync();

    {
      const float* h_new = ws + (((t & 1) == 0) ? WS_H1 : WS_H0);
      const float4* hv = (const float4*)h_new;
      for (int i = tid; i < 580; i += 256) s_buf4[i] = hv[i];
      __syncthreads();

      if (gt < 3072) {
        int i = gt / 768, cc = gt - i * 768;
        const float* wcol = W3 + (size_t)(i * 48) * 768 + cc;
        float acc = 0.f;
#pragma unroll 8
        for (int j = 0; j < 48; j++) acc += s_innov[j] * wcol[(size_t)j * 768];
        ws[WS_V + gt] = acc;
      } else if (gt < 3076) {
        int i = gt - 3072;
        float acc = 0.f;
        for (int j = 0; j < 48; j++) acc += s_innov[j] * b3[i * 48 + j];
        ws[WS_C + i] = acc;
      }

      for (int task = wave_g; task < 768; task += NW) {
        const float4* row = (const float4*)(W2 + (size_t)task * 2320);
        float acc = 0.f;
#pragma unroll 4
        for (int k = lane; k < 580; k += 64) acc += dot4(row[k], s_buf4[k]);
        acc = wred(acc);
        if (lane == 0) ws[WS_L2 + task] = fmaxf(acc + b2[task], 0.f);
      }
    }
    grid.sync();
  }
}

extern "C" void kernel_launch(void* const* d_in, const int* in_sizes, int n_in,
                              void* d_out, int out_size, void* d_ws, size_t ws_size,
                              hipStream_t stream) {
  const float* y_seq = (const float*)d_in[0];
  const float* x0    = (const float*)d_in[1];
  const float* h0    = (const float*)d_in[2];
  const float* A     = (const float*)d_in[3];
  const float* Cm    = (const float*)d_in[4];
  const float* W1    = (const float*)d_in[5];
  const float* b1    = (const float*)d_in[6];
  const float* W_ih  = (const float*)d_in[7];
  const float* W_hh  = (const float*)d_in[8];
  const float* b_ih  = (const float*)d_in[9];
  const float* b_hh  = (const float*)d_in[10];
  const float* W2    = (const float*)d_in[11];
  const float* b2    = (const float*)d_in[12];
  const float* W3    = (const float*)d_in[13];
  const float* b3    = (const float*)d_in[14];
  float* out = (float*)d_out;
  float* ws  = (float*)d_ws;
  char* wsb  = (char*)d_ws;

  if (ws_size >= NEED_MIN) {
    int use_w1p = (ws_size >= NEED_FULL) ? 1 : 0;
    hipFuncSetAttribute(reinterpret_cast<const void*>(knet2),
                        hipFuncAttributeMaxDynamicSharedMemorySize, DYN_LDS + 2048);
    hipMemsetAsync(wsb + O_SLOT, 0, 2048, stream);   // slots + epoch
    k_pack<<<8192, 256, 0, stream>>>(W_ih, (uint4*)(wsb + O_PIH),
                                     4160, 130, 435 * 130 * 64);
    k_pack<<<8192, 256, 0, stream>>>(W_hh, (uint4*)(wsb + O_PHH),
                                     2320, 73, 435 * 73 * 64);
    k_cvt<<<512, 256, 0, stream>>>((const float4*)W2,
                                   (ushort4*)(wsb + O_W2B), N_W2 / 4);
    if (use_w1p)
      k_cvtw1<<<(4160 * 56 + 255) / 256, 256, 0, stream>>>(
          W1, (unsigned short*)(wsb + O_W1P));
    k_h0<<<10, 256, 0, stream>>>(h0, (unsigned short*)(wsb + O_HB),
                                 (unsigned short*)(wsb + O_HB + HB_STR));

    void* args[] = { &y_seq, &x0, &h0, &A, &Cm, &W1, &b1, &b_ih, &b_hh,
                     &b2, &W3, &b3, &out, &wsb, &use_w1p };
    hipError_t err = hipLaunchCooperativeKernel(
        reinterpret_cast<void*>(knet2), dim3(256), dim3(1024), args, DYN_LDS, stream);
    if (err == hipSuccess) return;
  }

  {
    void* args[] = { &y_seq, &x0, &h0, &A, &Cm, &W1, &b1, &W_ih, &W_hh,
                     &b_ih, &b_hh, &W2, &b2, &W3, &b3, &out, &ws };
    hipLaunchCooperativeKernel(
        reinterpret_cast<void*>(knet), dim3(256), dim3(256), args, 0, stream);
  }
}